// Round 1
// baseline (4994.044 us; speedup 1.0000x reference)
//
#include <hip/hip_runtime.h>
#include <math.h>

#define N_EMBD 768
#define N_HEAD 12
#define HEAD_SIZE 64
#define SEQ_T 1024
#define BATCH 8
#define MROWS (BATCH * SEQ_T) /* 8192 */
#define C4 (4 * N_EMBD)       /* 3072 */
#define LN_EPS 1e-5f

// ---------------- LayerNorm: one block (256 thr) per row of 768 ----------------
__global__ __launch_bounds__(256) void ln_kernel(const float* __restrict__ x,
                                                 const float* __restrict__ g,
                                                 const float* __restrict__ b,
                                                 float* __restrict__ out) {
    int row = blockIdx.x;
    int tid = threadIdx.x;
    const float* xr = x + (size_t)row * N_EMBD;
    float x0 = xr[tid], x1 = xr[tid + 256], x2 = xr[tid + 512];

    __shared__ float red[256];
    red[tid] = x0 + x1 + x2;
    __syncthreads();
    for (int off = 128; off > 0; off >>= 1) {
        if (tid < off) red[tid] += red[tid + off];
        __syncthreads();
    }
    float mu = red[0] * (1.0f / N_EMBD);
    __syncthreads();

    float d0 = x0 - mu, d1 = x1 - mu, d2 = x2 - mu;
    red[tid] = d0 * d0 + d1 * d1 + d2 * d2;
    __syncthreads();
    for (int off = 128; off > 0; off >>= 1) {
        if (tid < off) red[tid] += red[tid + off];
        __syncthreads();
    }
    float var = red[0] * (1.0f / N_EMBD);
    float rs = rsqrtf(var + LN_EPS);

    float* orow = out + (size_t)row * N_EMBD;
    orow[tid]       = d0 * rs * g[tid]       + b[tid];
    orow[tid + 256] = d1 * rs * g[tid + 256] + b[tid + 256];
    orow[tid + 512] = d2 * rs * g[tid + 512] + b[tid + 512];
}

// ---------------- fp32 tiled GEMM: C = act(A@W + bias) + res ----------------
// act: 0 = none, 1 = exact gelu. bias/res may be null.
#define BM 64
#define BN 64
#define BK 16

__global__ __launch_bounds__(256) void gemm_kernel(const float* __restrict__ A,
                                                   const float* __restrict__ W,
                                                   const float* __restrict__ bias,
                                                   const float* __restrict__ res,
                                                   float* __restrict__ Cout,
                                                   int M, int N, int K, int act) {
    __shared__ float As[BK][BM + 1];
    __shared__ float Bs[BK][BN + 1];
    int tid = threadIdx.x;
    int tx = tid & 15, ty = tid >> 4;
    int brow = blockIdx.y * BM;
    int bcol = blockIdx.x * BN;

    float acc[4][4] = {};

    for (int k0 = 0; k0 < K; k0 += BK) {
#pragma unroll
        for (int i = tid; i < BM * BK; i += 256) {
            int r = i >> 4, c = i & 15;
            As[c][r] = A[(size_t)(brow + r) * K + k0 + c];
        }
#pragma unroll
        for (int i = tid; i < BK * BN; i += 256) {
            int r = i >> 6, c = i & 63;
            Bs[r][c] = W[(size_t)(k0 + r) * N + bcol + c];
        }
        __syncthreads();
#pragma unroll
        for (int kk = 0; kk < BK; kk++) {
            float a0 = As[kk][ty * 4 + 0];
            float a1 = As[kk][ty * 4 + 1];
            float a2 = As[kk][ty * 4 + 2];
            float a3 = As[kk][ty * 4 + 3];
            float b0 = Bs[kk][tx * 4 + 0];
            float b1 = Bs[kk][tx * 4 + 1];
            float b2 = Bs[kk][tx * 4 + 2];
            float b3 = Bs[kk][tx * 4 + 3];
            acc[0][0] += a0 * b0; acc[0][1] += a0 * b1; acc[0][2] += a0 * b2; acc[0][3] += a0 * b3;
            acc[1][0] += a1 * b0; acc[1][1] += a1 * b1; acc[1][2] += a1 * b2; acc[1][3] += a1 * b3;
            acc[2][0] += a2 * b0; acc[2][1] += a2 * b1; acc[2][2] += a2 * b2; acc[2][3] += a2 * b3;
            acc[3][0] += a3 * b0; acc[3][1] += a3 * b1; acc[3][2] += a3 * b2; acc[3][3] += a3 * b3;
        }
        __syncthreads();
    }

#pragma unroll
    for (int i = 0; i < 4; i++) {
#pragma unroll
        for (int j = 0; j < 4; j++) {
            int r = brow + ty * 4 + i;
            int c = bcol + tx * 4 + j;
            float vv = acc[i][j];
            if (bias) vv += bias[c];
            if (act == 1) vv = 0.5f * vv * (1.0f + erff(vv * 0.70710678118654752f));
            if (res) vv += res[(size_t)r * N + c];
            Cout[(size_t)r * N + c] = vv;
        }
    }
}

// ---------------- causal attention: one wave per query row ----------------
// grid = B*H*(T/4) blocks, 4 waves/block; wave w handles row t = rg*4+w.
__global__ __launch_bounds__(256) void attn_kernel(const float* __restrict__ q,
                                                   const float* __restrict__ k,
                                                   const float* __restrict__ v,
                                                   float* __restrict__ o) {
    __shared__ float sc[4][SEQ_T];
    __shared__ float qs[4][64];
    int tid = threadIdx.x;
    int lane = tid & 63;
    int w = tid >> 6;
    int bid = blockIdx.x;
    int rg = bid & (SEQ_T / 4 - 1); // % 256
    int bh = bid >> 8;              // / 256
    int hh = bh % N_HEAD;
    int b = bh / N_HEAD;
    int t = rg * 4 + w;
    const float scale = 0.03608439182435161f; // 768^-0.5 (note: C, not hs)

    size_t base_bt = ((size_t)b * SEQ_T + t) * N_EMBD + hh * HEAD_SIZE;
    qs[w][lane] = q[base_bt + lane];
    __syncthreads();

    // pass 1: scores + running max
    float mx = -1e30f;
    for (int s = lane; s <= t; s += 64) {
        const float* kr = k + ((size_t)b * SEQ_T + s) * N_EMBD + hh * HEAD_SIZE;
        float dot = 0.f;
#pragma unroll
        for (int d = 0; d < 64; d++) dot += qs[w][d] * kr[d];
        dot *= scale;
        sc[w][s] = dot;
        mx = fmaxf(mx, dot);
    }
#pragma unroll
    for (int off = 32; off; off >>= 1) mx = fmaxf(mx, __shfl_xor(mx, off));

    // pass 2: exp + sum (same lanes re-read their own writes)
    float sum = 0.f;
    for (int s = lane; s <= t; s += 64) {
        float e = __expf(sc[w][s] - mx);
        sc[w][s] = e;
        sum += e;
    }
#pragma unroll
    for (int off = 32; off; off >>= 1) sum += __shfl_xor(sum, off);
    float inv = 1.0f / sum;

    __syncthreads(); // cross-lane visibility of sc for pass 3

    // pass 3: o[d] = sum_s p_s * v[s][d]; lane = d (coalesced v reads)
    float accv = 0.f;
    for (int s = 0; s <= t; s++) {
        accv += sc[w][s] * v[((size_t)b * SEQ_T + s) * N_EMBD + hh * HEAD_SIZE + lane];
    }
    o[base_bt + lane] = accv * inv;
}

extern "C" void kernel_launch(void* const* d_in, const int* in_sizes, int n_in,
                              void* d_out, int out_size, void* d_ws, size_t ws_size,
                              hipStream_t stream) {
    const float* x   = (const float*)d_in[0];
    const float* Wq  = (const float*)d_in[1];
    const float* Wk  = (const float*)d_in[2];
    const float* Wv  = (const float*)d_in[3];
    const float* Wo  = (const float*)d_in[4];
    const float* bo  = (const float*)d_in[5];
    const float* W1  = (const float*)d_in[6];
    const float* b1  = (const float*)d_in[7];
    const float* W2  = (const float*)d_in[8];
    const float* b2  = (const float*)d_in[9];
    const float* g1  = (const float*)d_in[10];
    const float* be1 = (const float*)d_in[11];
    const float* g2  = (const float*)d_in[12];
    const float* be2 = (const float*)d_in[13];
    float* out = (float*)d_out;

    size_t S = (size_t)MROWS * N_EMBD; // 6291456 floats
    float* ws = (float*)d_ws;
    float* h   = ws;          // [M, C]
    float* q   = ws + S;      // [M, C]
    float* k   = ws + 2 * S;  // [M, C]
    float* v   = ws + 3 * S;  // [M, C]
    float* o   = ws + 4 * S;  // [M, C]
    float* x2  = ws + 5 * S;  // [M, C]
    float* ff1 = ws + S;      // [M, 4C] reuses q/k/v/o after attention

    dim3 blk(256);
    dim3 g768(N_EMBD / BN, MROWS / BM);
    dim3 g3072(C4 / BN, MROWS / BM);

    // h = LN1(x)
    ln_kernel<<<MROWS, blk, 0, stream>>>(x, g1, be1, h);
    // q,k,v = h @ W{q,k,v}
    gemm_kernel<<<g768, blk, 0, stream>>>(h, Wq, nullptr, nullptr, q, MROWS, N_EMBD, N_EMBD, 0);
    gemm_kernel<<<g768, blk, 0, stream>>>(h, Wk, nullptr, nullptr, k, MROWS, N_EMBD, N_EMBD, 0);
    gemm_kernel<<<g768, blk, 0, stream>>>(h, Wv, nullptr, nullptr, v, MROWS, N_EMBD, N_EMBD, 0);
    // o = causal softmax(q k^T * C^-0.5) v
    attn_kernel<<<BATCH * N_HEAD * (SEQ_T / 4), blk, 0, stream>>>(q, k, v, o);
    // x2 = x + o @ Wo + bo
    gemm_kernel<<<g768, blk, 0, stream>>>(o, Wo, bo, x, x2, MROWS, N_EMBD, N_EMBD, 0);
    // h = LN2(x2)
    ln_kernel<<<MROWS, blk, 0, stream>>>(x2, g2, be2, h);
    // ff1 = gelu(h @ W1 + b1)
    gemm_kernel<<<g3072, blk, 0, stream>>>(h, W1, b1, nullptr, ff1, MROWS, C4, N_EMBD, 1);
    // out = x2 + ff1 @ W2 + b2
    gemm_kernel<<<g768, blk, 0, stream>>>(ff1, W2, b2, x2, out, MROWS, N_EMBD, C4, 0);
}

// Round 2
// 1443.869 us; speedup vs baseline: 3.4588x; 3.4588x over previous
//
#include <hip/hip_runtime.h>
#include <math.h>
#include <stdint.h>

typedef unsigned short u16;
typedef unsigned int u32;
typedef __attribute__((ext_vector_type(8))) __bf16 bf16x8;
typedef __attribute__((ext_vector_type(4))) float f32x4;

#define AS1 __attribute__((address_space(1)))
#define AS3 __attribute__((address_space(3)))

__device__ __forceinline__ void stage16(const void* g, void* l) {
    __builtin_amdgcn_global_load_lds((const AS1 void*)(uintptr_t)g,
                                     (AS3 void*)(uintptr_t)l, 16, 0, 0);
}

__device__ __forceinline__ u16 f2bf(float f) {
    u32 u = __float_as_uint(f);
    u += 0x7fffu + ((u >> 16) & 1u);
    return (u16)(u >> 16);
}

// ---------------- LayerNorm: 256 thr per row of 768, bf16 out ----------------
__global__ __launch_bounds__(256) void ln_kernel(const float* __restrict__ x,
                                                 const float* __restrict__ g,
                                                 const float* __restrict__ b,
                                                 u16* __restrict__ out) {
    int row = blockIdx.x;
    int tid = threadIdx.x;
    const float* xr = x + (size_t)row * 768;
    float x0 = xr[tid], x1 = xr[tid + 256], x2 = xr[tid + 512];

    __shared__ float red[256];
    red[tid] = x0 + x1 + x2;
    __syncthreads();
    for (int off = 128; off > 0; off >>= 1) {
        if (tid < off) red[tid] += red[tid + off];
        __syncthreads();
    }
    float mu = red[0] * (1.0f / 768.0f);
    __syncthreads();

    float d0 = x0 - mu, d1 = x1 - mu, d2 = x2 - mu;
    red[tid] = d0 * d0 + d1 * d1 + d2 * d2;
    __syncthreads();
    for (int off = 128; off > 0; off >>= 1) {
        if (tid < off) red[tid] += red[tid + off];
        __syncthreads();
    }
    float var = red[0] * (1.0f / 768.0f);
    float rs = rsqrtf(var + 1e-5f);

    u16* orow = out + (size_t)row * 768;
    orow[tid]       = f2bf(d0 * rs * g[tid]       + b[tid]);
    orow[tid + 256] = f2bf(d1 * rs * g[tid + 256] + b[tid + 256]);
    orow[tid + 512] = f2bf(d2 * rs * g[tid + 512] + b[tid + 512]);
}

// ---------------- transpose + fp32->bf16 convert: W[K][N] -> Wt[N][K] ----------------
__global__ __launch_bounds__(256) void transpose_bf16(const float* __restrict__ W,
                                                      u16* __restrict__ Wt,
                                                      int K, int N) {
    __shared__ float t[32][33];
    int tx = threadIdx.x, ty = threadIdx.y;
    int n0 = blockIdx.x * 32, k0 = blockIdx.y * 32;
#pragma unroll
    for (int j = 0; j < 32; j += 8)
        t[ty + j][tx] = W[(size_t)(k0 + ty + j) * N + n0 + tx];
    __syncthreads();
#pragma unroll
    for (int j = 0; j < 32; j += 8)
        Wt[(size_t)(n0 + ty + j) * K + k0 + tx] = f2bf(t[tx][ty + j]);
}

// ---------------- bf16 MFMA GEMM: out = act(A @ Bt^T + bias) + res ----------------
// A: [M][K] bf16 row-major. Bt: [N][K] bf16 row-major (pre-transposed weights).
// 128x128 tile, BK=32, 4 waves (2x2), each wave 64x64 via 4x4 x (16x16x32) MFMA.
__global__ __launch_bounds__(256) void mfma_gemm(
    const u16* __restrict__ A, const u16* __restrict__ Bt,
    const float* __restrict__ bias, const float* __restrict__ res,
    float* __restrict__ outF, u16* __restrict__ outB,
    int N, int K, int act) {
    __shared__ char lds[16384];  // A tile [128][32]bf16 @0, B tile @8192
    const int tid = threadIdx.x, lane = tid & 63, wid = tid >> 6;
    const int l15 = lane & 15, lk = lane >> 4;
    const int wrow = (wid >> 1) * 64, wcol = (wid & 1) * 64;
    const int brow = blockIdx.y * 128, bcol = blockIdx.x * 128;
    const size_t K2 = (size_t)K * 2;

    const char* Abase = (const char*)A + (size_t)brow * K2;
    const char* Bbase = (const char*)Bt + (size_t)bcol * K2;

    // staging geometry: wave covers LDS bytes [wid*1024, +1024) x 2 rounds
    const int L0 = wid * 1024 + lane * 16;
    const int r0 = L0 >> 6, kb0 = L0 & 63;
    const int r1 = (L0 + 4096) >> 6, kb1 = (L0 + 4096) & 63;

    f32x4 acc[4][4] = {};

    for (int k0 = 0; k0 < K; k0 += 32) {
        __syncthreads();
        const char* Ak = Abase + (size_t)k0 * 2;
        const char* Bk = Bbase + (size_t)k0 * 2;
        stage16(Ak + (size_t)r0 * K2 + kb0, lds + wid * 1024);
        stage16(Ak + (size_t)r1 * K2 + kb1, lds + wid * 1024 + 4096);
        stage16(Bk + (size_t)r0 * K2 + kb0, lds + 8192 + wid * 1024);
        stage16(Bk + (size_t)r1 * K2 + kb1, lds + 8192 + wid * 1024 + 4096);
        asm volatile("s_waitcnt vmcnt(0)" ::: "memory");
        __syncthreads();

        bf16x8 af[4], bfv[4];
#pragma unroll
        for (int m = 0; m < 4; ++m)
            af[m] = *(const bf16x8*)(lds + (wrow + m * 16 + l15) * 64 + lk * 16);
#pragma unroll
        for (int n = 0; n < 4; ++n)
            bfv[n] = *(const bf16x8*)(lds + 8192 + (wcol + n * 16 + l15) * 64 + lk * 16);
#pragma unroll
        for (int m = 0; m < 4; ++m)
#pragma unroll
            for (int n = 0; n < 4; ++n)
                acc[m][n] = __builtin_amdgcn_mfma_f32_16x16x32_bf16(af[m], bfv[n], acc[m][n], 0, 0, 0);
    }

#pragma unroll
    for (int m = 0; m < 4; ++m)
#pragma unroll
        for (int n = 0; n < 4; ++n)
#pragma unroll
            for (int r = 0; r < 4; ++r) {
                int row = brow + wrow + m * 16 + lk * 4 + r;
                int col = bcol + wcol + n * 16 + l15;
                float v = acc[m][n][r];
                if (bias) v += bias[col];
                if (act) v = 0.5f * v * (1.0f + erff(v * 0.70710678118654752f));
                if (res) v += res[(size_t)row * N + col];
                if (outB) outB[(size_t)row * N + col] = f2bf(v);
                else outF[(size_t)row * N + col] = v;
            }
}

// ---------------- flash attention, fp32: 32 q-rows/block, 2 waves x 16 rows ----------------
// qkv: [B*T][2304] fp32 (q cols 0..767, k 768..1535, v 1536..2303), per head 64 cols.
__global__ __launch_bounds__(128) void attn_flash(const float* __restrict__ qkv,
                                                  u16* __restrict__ obf) {
    __shared__ float Qs[32][68];
    __shared__ float Ks[64][68];
    __shared__ float Vs[64][68];
    __shared__ float Ps[2][64][20];

    const int tid = threadIdx.x, lane = tid & 63, w = tid >> 6;
    const int qb = blockIdx.x, bh = blockIdx.y;
    const int h = bh % 12, b = bh / 12;
    const int t0 = qb * 32;
    const float scale = 0.03608439182435161f;  // 768^-0.5 (C, not hs, per reference)
    const size_t bbase = (size_t)b * 1024;

    for (int i = tid; i < 32 * 64; i += 128) {
        int r = i >> 6, d = i & 63;
        Qs[r][d] = qkv[(bbase + t0 + r) * 2304 + h * 64 + d];
    }

    float o_r[16], m_r[16], l_r[16];
#pragma unroll
    for (int r = 0; r < 16; ++r) { o_r[r] = 0.f; m_r[r] = -1e30f; l_r[r] = 0.f; }

    for (int s0 = 0; s0 <= t0 + 31; s0 += 64) {
        __syncthreads();
        for (int i = tid; i < 64 * 64; i += 128) {
            int r = i >> 6, d = i & 63;
            size_t base = (bbase + s0 + r) * 2304 + h * 64 + d;
            Ks[r][d] = qkv[base + 768];
            Vs[r][d] = qkv[base + 1536];
        }
        __syncthreads();

        // QK^T: lane = s, register-blocked over 16 rows
        float dot[16];
#pragma unroll
        for (int r = 0; r < 16; ++r) dot[r] = 0.f;
#pragma unroll 4
        for (int d4 = 0; d4 < 16; ++d4) {
            float4 kv = *(const float4*)&Ks[lane][d4 * 4];
#pragma unroll
            for (int r = 0; r < 16; ++r) {
                float4 qv = *(const float4*)&Qs[w * 16 + r][d4 * 4];
                dot[r] += kv.x * qv.x + kv.y * qv.y + kv.z * qv.z + kv.w * qv.w;
            }
        }

        // online softmax per row
#pragma unroll
        for (int r = 0; r < 16; ++r) {
            int t = t0 + w * 16 + r;
            float sv = ((s0 + lane) <= t) ? dot[r] * scale : -1e30f;
            float mx = sv;
#pragma unroll
            for (int off = 32; off; off >>= 1) mx = fmaxf(mx, __shfl_xor(mx, off));
            float mnew = fmaxf(m_r[r], mx);
            float p = __expf(sv - mnew);
            float corr = __expf(m_r[r] - mnew);
            m_r[r] = mnew;
            float ps = p;
#pragma unroll
            for (int off = 32; off; off >>= 1) ps += __shfl_xor(ps, off);
            l_r[r] = l_r[r] * corr + ps;
            o_r[r] *= corr;
            Ps[w][lane][r] = p;
        }

        // PV: lane = d
#pragma unroll 4
        for (int s = 0; s < 64; ++s) {
            float vv = Vs[s][lane];
            const float4* pp = (const float4*)&Ps[w][s][0];
            float4 p0 = pp[0], p1 = pp[1], p2 = pp[2], p3 = pp[3];
            o_r[0] += p0.x * vv;  o_r[1] += p0.y * vv;  o_r[2] += p0.z * vv;  o_r[3] += p0.w * vv;
            o_r[4] += p1.x * vv;  o_r[5] += p1.y * vv;  o_r[6] += p1.z * vv;  o_r[7] += p1.w * vv;
            o_r[8] += p2.x * vv;  o_r[9] += p2.y * vv;  o_r[10] += p2.z * vv; o_r[11] += p2.w * vv;
            o_r[12] += p3.x * vv; o_r[13] += p3.y * vv; o_r[14] += p3.z * vv; o_r[15] += p3.w * vv;
        }
    }

#pragma unroll
    for (int r = 0; r < 16; ++r) {
        int t = t0 + w * 16 + r;
        obf[(bbase + t) * 768 + h * 64 + lane] = f2bf(o_r[r] / l_r[r]);
    }
}

extern "C" void kernel_launch(void* const* d_in, const int* in_sizes, int n_in,
                              void* d_out, int out_size, void* d_ws, size_t ws_size,
                              hipStream_t stream) {
    const float* x   = (const float*)d_in[0];
    const float* Wq  = (const float*)d_in[1];
    const float* Wk  = (const float*)d_in[2];
    const float* Wv  = (const float*)d_in[3];
    const float* Wo  = (const float*)d_in[4];
    const float* bo  = (const float*)d_in[5];
    const float* W1  = (const float*)d_in[6];
    const float* b1  = (const float*)d_in[7];
    const float* W2  = (const float*)d_in[8];
    const float* b2  = (const float*)d_in[9];
    const float* g1  = (const float*)d_in[10];
    const float* be1 = (const float*)d_in[11];
    const float* g2  = (const float*)d_in[12];
    const float* be2 = (const float*)d_in[13];
    float* out = (float*)d_out;

    char* ws = (char*)d_ws;
    float* qkv  = (float*)(ws);              // [8192][2304] f32   75.5 MB
    float* x2   = (float*)(ws + 75497472);   // [8192][768]  f32   25.2 MB
    u16* h_bf   = (u16*)(ws + 100663296);    // [8192][768]  bf16  12.6 MB
    u16* o_bf   = (u16*)(ws + 113246208);    // [8192][768]  bf16  12.6 MB
    u16* Wqkvt  = (u16*)(ws + 125829120);    // [2304][768]  bf16   3.5 MB
    u16* W1t    = (u16*)(ws + 129368064);    // [3072][768]  bf16   4.7 MB
    u16* W2t    = (u16*)(ws + 134086656);    // [768][3072]  bf16   4.7 MB
    u16* Wot    = (u16*)(ws + 138805248);    // [768][768]   bf16   1.2 MB
    u16* ff1_bf = (u16*)(ws);                // [8192][3072] bf16  50.3 MB, reuses qkv

    dim3 tb(32, 8);
    transpose_bf16<<<dim3(24, 24), tb, 0, stream>>>(Wq, Wqkvt, 768, 768);
    transpose_bf16<<<dim3(24, 24), tb, 0, stream>>>(Wk, Wqkvt + 768 * 768, 768, 768);
    transpose_bf16<<<dim3(24, 24), tb, 0, stream>>>(Wv, Wqkvt + 2 * 768 * 768, 768, 768);
    transpose_bf16<<<dim3(24, 24), tb, 0, stream>>>(Wo, Wot, 768, 768);
    transpose_bf16<<<dim3(96, 24), tb, 0, stream>>>(W1, W1t, 768, 3072);
    transpose_bf16<<<dim3(24, 96), tb, 0, stream>>>(W2, W2t, 3072, 768);

    // h = LN1(x)  [bf16]
    ln_kernel<<<8192, 256, 0, stream>>>(x, g1, be1, h_bf);
    // qkv = h @ [Wq|Wk|Wv]   (fp32 out)
    mfma_gemm<<<dim3(18, 64), 256, 0, stream>>>(h_bf, Wqkvt, nullptr, nullptr, qkv, nullptr, 2304, 768, 0);
    // o = causal-softmax(q k^T * 768^-.5) v   (bf16 out)
    attn_flash<<<dim3(32, 96), 128, 0, stream>>>(qkv, o_bf);
    // x2 = x + o @ Wo + bo
    mfma_gemm<<<dim3(6, 64), 256, 0, stream>>>(o_bf, Wot, bo, x, x2, nullptr, 768, 768, 0);
    // h = LN2(x2)
    ln_kernel<<<8192, 256, 0, stream>>>(x2, g2, be2, h_bf);
    // ff1 = gelu(h @ W1 + b1)   (bf16 out)
    mfma_gemm<<<dim3(24, 64), 256, 0, stream>>>(h_bf, W1t, b1, nullptr, nullptr, ff1_bf, 3072, 768, 1);
    // out = x2 + ff1 @ W2 + b2
    mfma_gemm<<<dim3(6, 64), 256, 0, stream>>>(ff1_bf, W2t, b2, x2, out, nullptr, 768, 3072, 0);
}

// Round 3
// 463.864 us; speedup vs baseline: 10.7662x; 3.1127x over previous
//
#include <hip/hip_runtime.h>
#include <math.h>
#include <stdint.h>

typedef unsigned short u16;
typedef unsigned int u32;
typedef __attribute__((ext_vector_type(8))) __bf16 bf16x8;
typedef __attribute__((ext_vector_type(4))) float f32x4;

#define AS1 __attribute__((address_space(1)))
#define AS3 __attribute__((address_space(3)))

__device__ __forceinline__ void stage16(const void* g, void* l) {
    __builtin_amdgcn_global_load_lds((const AS1 void*)(uintptr_t)g,
                                     (AS3 void*)(uintptr_t)l, 16, 0, 0);
}

__device__ __forceinline__ u16 f2bf(float f) {
    u32 u = __float_as_uint(f);
    u += 0x7fffu + ((u >> 16) & 1u);
    return (u16)(u >> 16);
}

// ---------------- LayerNorm: 256 thr per row of 768, bf16 out ----------------
__global__ __launch_bounds__(256) void ln_kernel(const float* __restrict__ x,
                                                 const float* __restrict__ g,
                                                 const float* __restrict__ b,
                                                 u16* __restrict__ out) {
    int row = blockIdx.x;
    int tid = threadIdx.x;
    const float* xr = x + (size_t)row * 768;
    float x0 = xr[tid], x1 = xr[tid + 256], x2 = xr[tid + 512];

    __shared__ float red[256];
    red[tid] = x0 + x1 + x2;
    __syncthreads();
    for (int off = 128; off > 0; off >>= 1) {
        if (tid < off) red[tid] += red[tid + off];
        __syncthreads();
    }
    float mu = red[0] * (1.0f / 768.0f);
    __syncthreads();

    float d0 = x0 - mu, d1 = x1 - mu, d2 = x2 - mu;
    red[tid] = d0 * d0 + d1 * d1 + d2 * d2;
    __syncthreads();
    for (int off = 128; off > 0; off >>= 1) {
        if (tid < off) red[tid] += red[tid + off];
        __syncthreads();
    }
    float var = red[0] * (1.0f / 768.0f);
    float rs = rsqrtf(var + 1e-5f);

    u16* orow = out + (size_t)row * 768;
    orow[tid]       = f2bf(d0 * rs * g[tid]       + b[tid]);
    orow[tid + 256] = f2bf(d1 * rs * g[tid + 256] + b[tid + 256]);
    orow[tid + 512] = f2bf(d2 * rs * g[tid + 512] + b[tid + 512]);
}

// ---------------- transpose + fp32->bf16 convert: W[K][N] -> Wt[N][K] ----------------
__global__ __launch_bounds__(256) void transpose_bf16(const float* __restrict__ W,
                                                      u16* __restrict__ Wt,
                                                      int K, int N) {
    __shared__ float t[32][33];
    int tx = threadIdx.x, ty = threadIdx.y;
    int n0 = blockIdx.x * 32, k0 = blockIdx.y * 32;
#pragma unroll
    for (int j = 0; j < 32; j += 8)
        t[ty + j][tx] = W[(size_t)(k0 + ty + j) * N + n0 + tx];
    __syncthreads();
#pragma unroll
    for (int j = 0; j < 32; j += 8)
        Wt[(size_t)(n0 + ty + j) * K + k0 + tx] = f2bf(t[tx][ty + j]);
}

// ---------------- bf16 MFMA GEMM: out = act(A @ Bt^T + bias) + res ----------------
__global__ __launch_bounds__(256) void mfma_gemm(
    const u16* __restrict__ A, const u16* __restrict__ Bt,
    const float* __restrict__ bias, const float* __restrict__ res,
    float* __restrict__ outF, u16* __restrict__ outB,
    int N, int K, int act) {
    __shared__ char lds[16384];  // A tile [128][32]bf16 @0, B tile @8192
    const int tid = threadIdx.x, lane = tid & 63, wid = tid >> 6;
    const int l15 = lane & 15, lk = lane >> 4;
    const int wrow = (wid >> 1) * 64, wcol = (wid & 1) * 64;
    const int brow = blockIdx.y * 128, bcol = blockIdx.x * 128;
    const size_t K2 = (size_t)K * 2;

    const char* Abase = (const char*)A + (size_t)brow * K2;
    const char* Bbase = (const char*)Bt + (size_t)bcol * K2;

    const int L0 = wid * 1024 + lane * 16;
    const int r0 = L0 >> 6, kb0 = L0 & 63;
    const int r1 = (L0 + 4096) >> 6, kb1 = (L0 + 4096) & 63;

    f32x4 acc[4][4] = {};

    for (int k0 = 0; k0 < K; k0 += 32) {
        __syncthreads();
        const char* Ak = Abase + (size_t)k0 * 2;
        const char* Bk = Bbase + (size_t)k0 * 2;
        stage16(Ak + (size_t)r0 * K2 + kb0, lds + wid * 1024);
        stage16(Ak + (size_t)r1 * K2 + kb1, lds + wid * 1024 + 4096);
        stage16(Bk + (size_t)r0 * K2 + kb0, lds + 8192 + wid * 1024);
        stage16(Bk + (size_t)r1 * K2 + kb1, lds + 8192 + wid * 1024 + 4096);
        asm volatile("s_waitcnt vmcnt(0)" ::: "memory");
        __syncthreads();

        bf16x8 af[4], bfv[4];
#pragma unroll
        for (int m = 0; m < 4; ++m)
            af[m] = *(const bf16x8*)(lds + (wrow + m * 16 + l15) * 64 + lk * 16);
#pragma unroll
        for (int n = 0; n < 4; ++n)
            bfv[n] = *(const bf16x8*)(lds + 8192 + (wcol + n * 16 + l15) * 64 + lk * 16);
#pragma unroll
        for (int m = 0; m < 4; ++m)
#pragma unroll
            for (int n = 0; n < 4; ++n)
                acc[m][n] = __builtin_amdgcn_mfma_f32_16x16x32_bf16(af[m], bfv[n], acc[m][n], 0, 0, 0);
    }

#pragma unroll
    for (int m = 0; m < 4; ++m)
#pragma unroll
        for (int n = 0; n < 4; ++n)
#pragma unroll
            for (int r = 0; r < 4; ++r) {
                int row = brow + wrow + m * 16 + lk * 4 + r;
                int col = bcol + wcol + n * 16 + l15;
                float v = acc[m][n][r];
                if (bias) v += bias[col];
                if (act) v = 0.5f * v * (1.0f + erff(v * 0.70710678118654752f));
                if (res) v += res[(size_t)row * N + col];
                if (outB) outB[(size_t)row * N + col] = f2bf(v);
                else outF[(size_t)row * N + col] = v;
            }
}

// ---------------- MFMA flash attention ----------------
// qkv bf16 [8192][2304] (q|k|v, each 768 = 12 heads x 64).
// Block: 64 q-rows x one (b,h). 4 waves, wave w owns q-rows 16w..16w+15.
// LDS: K tile [64s][64d] swizzled @0 (8KB), Vt [64d][64s] swizzled @8192 (8KB),
//      P per-wave [16q][64s] bf16 @16384+w*2048 (8KB total). 24KB.
__global__ __launch_bounds__(256) void attn_mfma(const u16* __restrict__ qkv,
                                                 u16* __restrict__ obf) {
    __shared__ char lds[24576];
    const int tid = threadIdx.x, lane = tid & 63, w = tid >> 6;
    const int g = lane >> 4, l15 = lane & 15;
    const int qb = (int)(gridDim.x - 1 - blockIdx.x);  // heavy blocks first
    const int bh = blockIdx.y;
    const int h = bh % 12, b = bh / 12;
    const int t0 = qb * 64;
    const float scale = 0.03608439182435161f;  // 768^-0.5 (C, not hs, per reference)

    // Q fragments (A-operand) in registers: row = t0 + 16w + l15, k = 8g+j (+32)
    const size_t qrow = ((size_t)b * 1024 + t0 + 16 * w + l15) * 2304 + h * 64;
    const bf16x8 qf0 = *(const bf16x8*)(qkv + qrow + 8 * g);
    const bf16x8 qf1 = *(const bf16x8*)(qkv + qrow + 8 * g + 32);

    // staging coords: per round, thread handles row (rr*32 + tid>>3), 8 elems at (tid&7)*8
    const int srow = tid >> 3;
    const int scol = (tid & 7) * 8;
    const int swzK = (srow & 7) << 4;           // (row&7)<<4, same both rounds
    const size_t kvbase = (size_t)b * 1024 * 2304 + 768 + h * 64;

    const int swzA = (l15 & 7) << 4;            // row-swizzle for K-frag/P-frag reads

    float m_r[4] = {-1e30f, -1e30f, -1e30f, -1e30f};
    float l_r[4] = {0.f, 0.f, 0.f, 0.f};
    f32x4 oacc[4] = {};

    char* Pw = lds + 16384 + w * 2048;

    for (int c = 0; c <= qb; ++c) {
        const int s0 = c * 64;
        __syncthreads();
#pragma unroll
        for (int rr = 0; rr < 2; ++rr) {
            const int row = rr * 32 + srow;
            const u16* kp = qkv + kvbase + (size_t)(s0 + row) * 2304 + scol;
            union { bf16x8 v; u16 u[8]; } kv, vv;
            kv.v = *(const bf16x8*)kp;
            vv.v = *(const bf16x8*)(kp + 768);
            *(bf16x8*)(lds + row * 128 + ((scol * 2) ^ swzK)) = kv.v;
#pragma unroll
            for (int j = 0; j < 8; ++j) {
                const int d = scol + j;
                *(u16*)(lds + 8192 + d * 128 +
                        ((row * 2) ^ (((d ^ (d >> 3)) & 7) << 4))) = vv.u[j];
            }
        }
        __syncthreads();

        // S = Q K^T : D[q=4g+r][s=l15+16st]
        f32x4 sacc[4] = {};
#pragma unroll
        for (int st = 0; st < 4; ++st) {
            const char* krow = lds + (l15 + 16 * st) * 128;
            const bf16x8 kf0 = *(const bf16x8*)(krow + ((16 * g) ^ swzA));
            const bf16x8 kf1 = *(const bf16x8*)(krow + ((16 * g + 64) ^ swzA));
            sacc[st] = __builtin_amdgcn_mfma_f32_16x16x32_bf16(qf0, kf0, sacc[st], 0, 0, 0);
            sacc[st] = __builtin_amdgcn_mfma_f32_16x16x32_bf16(qf1, kf1, sacc[st], 0, 0, 0);
        }

        const bool diag = (c == qb);
#pragma unroll
        for (int r = 0; r < 4; ++r) {
            float sv0 = sacc[0][r] * scale, sv1 = sacc[1][r] * scale;
            float sv2 = sacc[2][r] * scale, sv3 = sacc[3][r] * scale;
            if (diag) {
                const int trel = 16 * w + 4 * g + r;
                if (l15 +  0 > trel) sv0 = -1e30f;
                if (l15 + 16 > trel) sv1 = -1e30f;
                if (l15 + 32 > trel) sv2 = -1e30f;
                if (l15 + 48 > trel) sv3 = -1e30f;
            }
            float mx = fmaxf(fmaxf(sv0, sv1), fmaxf(sv2, sv3));
#pragma unroll
            for (int off = 1; off < 16; off <<= 1) mx = fmaxf(mx, __shfl_xor(mx, off));
            const float mnew = fmaxf(m_r[r], mx);
            const float corr = __expf(m_r[r] - mnew);
            const float p0 = __expf(sv0 - mnew), p1 = __expf(sv1 - mnew);
            const float p2 = __expf(sv2 - mnew), p3 = __expf(sv3 - mnew);
            float ps = p0 + p1 + p2 + p3;
#pragma unroll
            for (int off = 1; off < 16; off <<= 1) ps += __shfl_xor(ps, off);
            l_r[r] = l_r[r] * corr + ps;
            m_r[r] = mnew;
            oacc[0][r] *= corr; oacc[1][r] *= corr;
            oacc[2][r] *= corr; oacc[3][r] *= corr;
            // write P[q=4g+r][s=l15+16st] bf16, swizzled
            const int q = 4 * g + r;
            char* pr = Pw + q * 128;
            const int sw = (q & 7) << 4;
            *(u16*)(pr + ((l15 * 2 +  0) ^ sw)) = f2bf(p0);
            *(u16*)(pr + ((l15 * 2 + 32) ^ sw)) = f2bf(p1);
            *(u16*)(pr + ((l15 * 2 + 64) ^ sw)) = f2bf(p2);
            *(u16*)(pr + ((l15 * 2 + 96) ^ sw)) = f2bf(p3);
        }

        // O += P V : A = P[16q][32s-chunk], B = Vt rows (d-major)
#pragma unroll
        for (int kc = 0; kc < 2; ++kc) {
            const bf16x8 pa = *(const bf16x8*)(Pw + l15 * 128 + ((16 * g + 64 * kc) ^ swzA));
#pragma unroll
            for (int dt = 0; dt < 4; ++dt) {
                const int d = l15 + 16 * dt;
                const bf16x8 vf = *(const bf16x8*)(lds + 8192 + d * 128 +
                                   ((16 * g + 64 * kc) ^ (((d ^ (d >> 3)) & 7) << 4)));
                oacc[dt] = __builtin_amdgcn_mfma_f32_16x16x32_bf16(pa, vf, oacc[dt], 0, 0, 0);
            }
        }
    }

    // epilogue: O[q][d] / l[q] -> obf
    const size_t orow0 = ((size_t)b * 1024 + t0 + 16 * w) * 768 + h * 64;
#pragma unroll
    for (int r = 0; r < 4; ++r) {
        const float inv = 1.0f / l_r[r];
        const size_t orow = orow0 + (size_t)(4 * g + r) * 768;
#pragma unroll
        for (int dt = 0; dt < 4; ++dt)
            obf[orow + 16 * dt + l15] = f2bf(oacc[dt][r] * inv);
    }
}

extern "C" void kernel_launch(void* const* d_in, const int* in_sizes, int n_in,
                              void* d_out, int out_size, void* d_ws, size_t ws_size,
                              hipStream_t stream) {
    const float* x   = (const float*)d_in[0];
    const float* Wq  = (const float*)d_in[1];
    const float* Wk  = (const float*)d_in[2];
    const float* Wv  = (const float*)d_in[3];
    const float* Wo  = (const float*)d_in[4];
    const float* bo  = (const float*)d_in[5];
    const float* W1  = (const float*)d_in[6];
    const float* b1  = (const float*)d_in[7];
    const float* W2  = (const float*)d_in[8];
    const float* b2  = (const float*)d_in[9];
    const float* g1  = (const float*)d_in[10];
    const float* be1 = (const float*)d_in[11];
    const float* g2  = (const float*)d_in[12];
    const float* be2 = (const float*)d_in[13];
    float* out = (float*)d_out;

    char* ws = (char*)d_ws;
    u16* qkv_bf = (u16*)(ws);              // [8192][2304] bf16  37.7MB (dead after attn)
    u16* ff1_bf = (u16*)(ws);              // [8192][3072] bf16  50.3MB (reuses qkv region)
    float* x2   = (float*)(ws + 50331648); // [8192][768]  f32   25.2MB
    u16* h_bf   = (u16*)(ws + 75497472);   // [8192][768]  bf16  12.6MB
    u16* o_bf   = (u16*)(ws + 88080384);   // [8192][768]  bf16  12.6MB
    u16* Wqkvt  = (u16*)(ws + 100663296);  // [2304][768]  bf16   3.5MB
    u16* W1t    = (u16*)(ws + 104202240);  // [3072][768]  bf16   4.7MB
    u16* W2t    = (u16*)(ws + 108920832);  // [768][3072]  bf16   4.7MB
    u16* Wot    = (u16*)(ws + 113639424);  // [768][768]   bf16   1.2MB

    dim3 tb(32, 8);
    transpose_bf16<<<dim3(24, 24), tb, 0, stream>>>(Wq, Wqkvt, 768, 768);
    transpose_bf16<<<dim3(24, 24), tb, 0, stream>>>(Wk, Wqkvt + 768 * 768, 768, 768);
    transpose_bf16<<<dim3(24, 24), tb, 0, stream>>>(Wv, Wqkvt + 2 * 768 * 768, 768, 768);
    transpose_bf16<<<dim3(24, 24), tb, 0, stream>>>(Wo, Wot, 768, 768);
    transpose_bf16<<<dim3(96, 24), tb, 0, stream>>>(W1, W1t, 768, 3072);
    transpose_bf16<<<dim3(24, 96), tb, 0, stream>>>(W2, W2t, 3072, 768);

    // h = LN1(x)
    ln_kernel<<<8192, 256, 0, stream>>>(x, g1, be1, h_bf);
    // qkv = h @ [Wq|Wk|Wv]  (bf16 out)
    mfma_gemm<<<dim3(18, 64), 256, 0, stream>>>(h_bf, Wqkvt, nullptr, nullptr, nullptr, qkv_bf, 2304, 768, 0);
    // o = causal-softmax(q k^T * 768^-.5) v  (bf16 out)
    attn_mfma<<<dim3(16, 96), 256, 0, stream>>>(qkv_bf, o_bf);
    // x2 = x + o @ Wo + bo
    mfma_gemm<<<dim3(6, 64), 256, 0, stream>>>(o_bf, Wot, bo, x, x2, nullptr, 768, 768, 0);
    // h = LN2(x2)
    ln_kernel<<<8192, 256, 0, stream>>>(x2, g2, be2, h_bf);
    // ff1 = gelu(h @ W1 + b1)  (bf16 out)
    mfma_gemm<<<dim3(24, 64), 256, 0, stream>>>(h_bf, W1t, b1, nullptr, nullptr, ff1_bf, 3072, 768, 1);
    // out = x2 + ff1 @ W2 + b2
    mfma_gemm<<<dim3(6, 64), 256, 0, stream>>>(ff1_bf, W2t, b2, x2, out, nullptr, 768, 3072, 0);
}

// Round 4
// 432.481 us; speedup vs baseline: 11.5474x; 1.0726x over previous
//
#include <hip/hip_runtime.h>
#include <math.h>
#include <stdint.h>

typedef unsigned short u16;
typedef unsigned int u32;
typedef __attribute__((ext_vector_type(8))) __bf16 bf16x8;
typedef __attribute__((ext_vector_type(4))) float f32x4;

#define AS1 __attribute__((address_space(1)))
#define AS3 __attribute__((address_space(3)))

__device__ __forceinline__ void stage16(const void* g, void* l) {
    __builtin_amdgcn_global_load_lds((const AS1 void*)(uintptr_t)g,
                                     (AS3 void*)(uintptr_t)l, 16, 0, 0);
}

__device__ __forceinline__ u16 f2bf(float f) {
    u32 u = __float_as_uint(f);
    u += 0x7fffu + ((u >> 16) & 1u);
    return (u16)(u >> 16);
}

// ---------------- LayerNorm: 256 thr per row of 768, bf16 out ----------------
__global__ __launch_bounds__(256) void ln_kernel(const float* __restrict__ x,
                                                 const float* __restrict__ g,
                                                 const float* __restrict__ b,
                                                 u16* __restrict__ out) {
    int row = blockIdx.x;
    int tid = threadIdx.x;
    const float* xr = x + (size_t)row * 768;
    float x0 = xr[tid], x1 = xr[tid + 256], x2 = xr[tid + 512];

    __shared__ float red[256];
    red[tid] = x0 + x1 + x2;
    __syncthreads();
    for (int off = 128; off > 0; off >>= 1) {
        if (tid < off) red[tid] += red[tid + off];
        __syncthreads();
    }
    float mu = red[0] * (1.0f / 768.0f);
    __syncthreads();

    float d0 = x0 - mu, d1 = x1 - mu, d2 = x2 - mu;
    red[tid] = d0 * d0 + d1 * d1 + d2 * d2;
    __syncthreads();
    for (int off = 128; off > 0; off >>= 1) {
        if (tid < off) red[tid] += red[tid + off];
        __syncthreads();
    }
    float var = red[0] * (1.0f / 768.0f);
    float rs = rsqrtf(var + 1e-5f);

    u16* orow = out + (size_t)row * 768;
    orow[tid]       = f2bf(d0 * rs * g[tid]       + b[tid]);
    orow[tid + 256] = f2bf(d1 * rs * g[tid + 256] + b[tid + 256]);
    orow[tid + 512] = f2bf(d2 * rs * g[tid + 512] + b[tid + 512]);
}

// ---------------- transpose + fp32->bf16 convert: W[K][N] -> Wt[N][K] ----------------
__global__ __launch_bounds__(256) void transpose_bf16(const float* __restrict__ W,
                                                      u16* __restrict__ Wt,
                                                      int K, int N) {
    __shared__ float t[32][33];
    int tx = threadIdx.x, ty = threadIdx.y;
    int n0 = blockIdx.x * 32, k0 = blockIdx.y * 32;
#pragma unroll
    for (int j = 0; j < 32; j += 8)
        t[ty + j][tx] = W[(size_t)(k0 + ty + j) * N + n0 + tx];
    __syncthreads();
#pragma unroll
    for (int j = 0; j < 32; j += 8)
        Wt[(size_t)(n0 + ty + j) * K + k0 + tx] = f2bf(t[tx][ty + j]);
}

// ---------------- bf16 MFMA GEMM, double-buffered BK=64, swizzled LDS ----------------
// A: [M][K] bf16 row-major. Bt: [N][K] bf16 row-major.
// 128x128 tile, 4 waves (2x2), wave = 64x64 out. LDS: 2 x (A 16KB + B 16KB) = 64KB.
// Layout: row stride 128B, byte-in-row XOR-swizzled by ((row&7)<<4); staging uses
// pre-swizzled global source addresses (global_load_lds writes linearly).
__global__ __launch_bounds__(256) void mfma_gemm(
    const u16* __restrict__ A, const u16* __restrict__ Bt,
    const float* __restrict__ bias, const float* __restrict__ res,
    float* __restrict__ outF, u16* __restrict__ outB,
    int N, int K, int act) {
    __shared__ char lds[65536];
    const int tid = threadIdx.x, lane = tid & 63, wid = tid >> 6;
    const int l15 = lane & 15, lk = lane >> 4;
    const int wrow = (wid >> 1) * 64, wcol = (wid & 1) * 64;
    const int brow = blockIdx.y * 128, bcol = blockIdx.x * 128;
    const size_t K2 = (size_t)K * 2;

    const char* Abase = (const char*)A + (size_t)brow * K2;
    const char* Bbase = (const char*)Bt + (size_t)bcol * K2;

    // staging geometry: 4 rounds x 256 thr x 16B = 16KB per tile.
    // LDS linear L = j*4096 + tid*16; logical row = L>>7, col = (L&127)^((row&7)<<4)
    int srow[4], scol[4];
#pragma unroll
    for (int j = 0; j < 4; ++j) {
        const int L = j * 4096 + tid * 16;
        srow[j] = L >> 7;
        scol[j] = (L & 127) ^ ((srow[j] & 7) << 4);
    }

    f32x4 acc[4][4] = {};
    const int nt = K >> 6;
    int cur = 0;

    // prologue: stage tile 0 into buf 0
#pragma unroll
    for (int j = 0; j < 4; ++j) {
        const size_t off = (size_t)srow[j] * K2 + scol[j];
        stage16(Abase + off, lds + j * 4096 + tid * 16);
        stage16(Bbase + off, lds + 16384 + j * 4096 + tid * 16);
    }
    __syncthreads();

    for (int t = 0; t < nt; ++t) {
        if (t + 1 < nt) {
            const char* An = Abase + (size_t)(t + 1) * 128;
            const char* Bn = Bbase + (size_t)(t + 1) * 128;
            char* dst = lds + (cur ^ 1) * 32768;
#pragma unroll
            for (int j = 0; j < 4; ++j) {
                const size_t off = (size_t)srow[j] * K2 + scol[j];
                stage16(An + off, dst + j * 4096 + tid * 16);
                stage16(Bn + off, dst + 16384 + j * 4096 + tid * 16);
            }
        }

        const char* As = lds + cur * 32768;
        const char* Bs = As + 16384;
#pragma unroll
        for (int kc = 0; kc < 2; ++kc) {
            bf16x8 af[4], bfv[4];
#pragma unroll
            for (int m = 0; m < 4; ++m) {
                const int row = wrow + m * 16 + l15;
                af[m] = *(const bf16x8*)(As + row * 128 +
                                         ((kc * 64 + lk * 16) ^ ((row & 7) << 4)));
            }
#pragma unroll
            for (int n = 0; n < 4; ++n) {
                const int row = wcol + n * 16 + l15;
                bfv[n] = *(const bf16x8*)(Bs + row * 128 +
                                          ((kc * 64 + lk * 16) ^ ((row & 7) << 4)));
            }
#pragma unroll
            for (int m = 0; m < 4; ++m)
#pragma unroll
                for (int n = 0; n < 4; ++n)
                    acc[m][n] = __builtin_amdgcn_mfma_f32_16x16x32_bf16(af[m], bfv[n], acc[m][n], 0, 0, 0);
        }
        __syncthreads();  // drains vmcnt (prefetch) + lgkm; one barrier per K-step
        cur ^= 1;
    }

#pragma unroll
    for (int m = 0; m < 4; ++m)
#pragma unroll
        for (int n = 0; n < 4; ++n)
#pragma unroll
            for (int r = 0; r < 4; ++r) {
                int row = brow + wrow + m * 16 + lk * 4 + r;
                int col = bcol + wcol + n * 16 + l15;
                float v = acc[m][n][r];
                if (bias) v += bias[col];
                if (act) v = 0.5f * v * (1.0f + erff(v * 0.70710678118654752f));
                if (res) v += res[(size_t)row * N + col];
                if (outB) outB[(size_t)row * N + col] = f2bf(v);
                else outF[(size_t)row * N + col] = v;
            }
}

// ---------------- MFMA flash attention ----------------
// qkv bf16 [8192][2304] (q|k|v, each 768 = 12 heads x 64).
// Block: 64 q-rows x one (b,h). 4 waves, wave w owns q-rows 16w..16w+15.
__global__ __launch_bounds__(256) void attn_mfma(const u16* __restrict__ qkv,
                                                 u16* __restrict__ obf) {
    __shared__ char lds[24576];
    const int tid = threadIdx.x, lane = tid & 63, w = tid >> 6;
    const int g = lane >> 4, l15 = lane & 15;
    const int qb = (int)(gridDim.x - 1 - blockIdx.x);  // heavy blocks first
    const int bh = blockIdx.y;
    const int h = bh % 12, b = bh / 12;
    const int t0 = qb * 64;
    const float scale = 0.03608439182435161f;  // 768^-0.5 (C, not hs, per reference)

    const size_t qrow = ((size_t)b * 1024 + t0 + 16 * w + l15) * 2304 + h * 64;
    const bf16x8 qf0 = *(const bf16x8*)(qkv + qrow + 8 * g);
    const bf16x8 qf1 = *(const bf16x8*)(qkv + qrow + 8 * g + 32);

    const int srow = tid >> 3;
    const int scol = (tid & 7) * 8;
    const int swzK = (srow & 7) << 4;
    const size_t kvbase = (size_t)b * 1024 * 2304 + 768 + h * 64;

    const int swzA = (l15 & 7) << 4;

    float m_r[4] = {-1e30f, -1e30f, -1e30f, -1e30f};
    float l_r[4] = {0.f, 0.f, 0.f, 0.f};
    f32x4 oacc[4] = {};

    char* Pw = lds + 16384 + w * 2048;

    for (int c = 0; c <= qb; ++c) {
        const int s0 = c * 64;
        __syncthreads();
#pragma unroll
        for (int rr = 0; rr < 2; ++rr) {
            const int row = rr * 32 + srow;
            const u16* kp = qkv + kvbase + (size_t)(s0 + row) * 2304 + scol;
            union { bf16x8 v; u16 u[8]; } kv, vv;
            kv.v = *(const bf16x8*)kp;
            vv.v = *(const bf16x8*)(kp + 768);
            *(bf16x8*)(lds + row * 128 + ((scol * 2) ^ swzK)) = kv.v;
#pragma unroll
            for (int j = 0; j < 8; ++j) {
                const int d = scol + j;
                *(u16*)(lds + 8192 + d * 128 +
                        ((row * 2) ^ (((d ^ (d >> 3)) & 7) << 4))) = vv.u[j];
            }
        }
        __syncthreads();

        f32x4 sacc[4] = {};
#pragma unroll
        for (int st = 0; st < 4; ++st) {
            const char* krow = lds + (l15 + 16 * st) * 128;
            const bf16x8 kf0 = *(const bf16x8*)(krow + ((16 * g) ^ swzA));
            const bf16x8 kf1 = *(const bf16x8*)(krow + ((16 * g + 64) ^ swzA));
            sacc[st] = __builtin_amdgcn_mfma_f32_16x16x32_bf16(qf0, kf0, sacc[st], 0, 0, 0);
            sacc[st] = __builtin_amdgcn_mfma_f32_16x16x32_bf16(qf1, kf1, sacc[st], 0, 0, 0);
        }

        const bool diag = (c == qb);
#pragma unroll
        for (int r = 0; r < 4; ++r) {
            float sv0 = sacc[0][r] * scale, sv1 = sacc[1][r] * scale;
            float sv2 = sacc[2][r] * scale, sv3 = sacc[3][r] * scale;
            if (diag) {
                const int trel = 16 * w + 4 * g + r;
                if (l15 +  0 > trel) sv0 = -1e30f;
                if (l15 + 16 > trel) sv1 = -1e30f;
                if (l15 + 32 > trel) sv2 = -1e30f;
                if (l15 + 48 > trel) sv3 = -1e30f;
            }
            float mx = fmaxf(fmaxf(sv0, sv1), fmaxf(sv2, sv3));
#pragma unroll
            for (int off = 1; off < 16; off <<= 1) mx = fmaxf(mx, __shfl_xor(mx, off));
            const float mnew = fmaxf(m_r[r], mx);
            const float corr = __expf(m_r[r] - mnew);
            const float p0 = __expf(sv0 - mnew), p1 = __expf(sv1 - mnew);
            const float p2 = __expf(sv2 - mnew), p3 = __expf(sv3 - mnew);
            float ps = p0 + p1 + p2 + p3;
#pragma unroll
            for (int off = 1; off < 16; off <<= 1) ps += __shfl_xor(ps, off);
            l_r[r] = l_r[r] * corr + ps;
            m_r[r] = mnew;
            oacc[0][r] *= corr; oacc[1][r] *= corr;
            oacc[2][r] *= corr; oacc[3][r] *= corr;
            const int q = 4 * g + r;
            char* pr = Pw + q * 128;
            const int sw = (q & 7) << 4;
            *(u16*)(pr + ((l15 * 2 +  0) ^ sw)) = f2bf(p0);
            *(u16*)(pr + ((l15 * 2 + 32) ^ sw)) = f2bf(p1);
            *(u16*)(pr + ((l15 * 2 + 64) ^ sw)) = f2bf(p2);
            *(u16*)(pr + ((l15 * 2 + 96) ^ sw)) = f2bf(p3);
        }

#pragma unroll
        for (int kc = 0; kc < 2; ++kc) {
            const bf16x8 pa = *(const bf16x8*)(Pw + l15 * 128 + ((16 * g + 64 * kc) ^ swzA));
#pragma unroll
            for (int dt = 0; dt < 4; ++dt) {
                const int d = l15 + 16 * dt;
                const bf16x8 vf = *(const bf16x8*)(lds + 8192 + d * 128 +
                                   ((16 * g + 64 * kc) ^ (((d ^ (d >> 3)) & 7) << 4)));
                oacc[dt] = __builtin_amdgcn_mfma_f32_16x16x32_bf16(pa, vf, oacc[dt], 0, 0, 0);
            }
        }
    }

    const size_t orow0 = ((size_t)b * 1024 + t0 + 16 * w) * 768 + h * 64;
#pragma unroll
    for (int r = 0; r < 4; ++r) {
        const float inv = 1.0f / l_r[r];
        const size_t orow = orow0 + (size_t)(4 * g + r) * 768;
#pragma unroll
        for (int dt = 0; dt < 4; ++dt)
            obf[orow + 16 * dt + l15] = f2bf(oacc[dt][r] * inv);
    }
}

extern "C" void kernel_launch(void* const* d_in, const int* in_sizes, int n_in,
                              void* d_out, int out_size, void* d_ws, size_t ws_size,
                              hipStream_t stream) {
    const float* x   = (const float*)d_in[0];
    const float* Wq  = (const float*)d_in[1];
    const float* Wk  = (const float*)d_in[2];
    const float* Wv  = (const float*)d_in[3];
    const float* Wo  = (const float*)d_in[4];
    const float* bo  = (const float*)d_in[5];
    const float* W1  = (const float*)d_in[6];
    const float* b1  = (const float*)d_in[7];
    const float* W2  = (const float*)d_in[8];
    const float* b2  = (const float*)d_in[9];
    const float* g1  = (const float*)d_in[10];
    const float* be1 = (const float*)d_in[11];
    const float* g2  = (const float*)d_in[12];
    const float* be2 = (const float*)d_in[13];
    float* out = (float*)d_out;

    char* ws = (char*)d_ws;
    u16* qkv_bf = (u16*)(ws);              // [8192][2304] bf16  37.7MB (dead after attn)
    u16* ff1_bf = (u16*)(ws);              // [8192][3072] bf16  50.3MB (reuses qkv region)
    float* x2   = (float*)(ws + 50331648); // [8192][768]  f32   25.2MB
    u16* h_bf   = (u16*)(ws + 75497472);   // [8192][768]  bf16  12.6MB
    u16* o_bf   = (u16*)(ws + 88080384);   // [8192][768]  bf16  12.6MB
    u16* Wqkvt  = (u16*)(ws + 100663296);  // [2304][768]  bf16   3.5MB
    u16* W1t    = (u16*)(ws + 104202240);  // [3072][768]  bf16   4.7MB
    u16* W2t    = (u16*)(ws + 108920832);  // [768][3072]  bf16   4.7MB
    u16* Wot    = (u16*)(ws + 113639424);  // [768][768]   bf16   1.2MB

    dim3 tb(32, 8);
    transpose_bf16<<<dim3(24, 24), tb, 0, stream>>>(Wq, Wqkvt, 768, 768);
    transpose_bf16<<<dim3(24, 24), tb, 0, stream>>>(Wk, Wqkvt + 768 * 768, 768, 768);
    transpose_bf16<<<dim3(24, 24), tb, 0, stream>>>(Wv, Wqkvt + 2 * 768 * 768, 768, 768);
    transpose_bf16<<<dim3(24, 24), tb, 0, stream>>>(Wo, Wot, 768, 768);
    transpose_bf16<<<dim3(96, 24), tb, 0, stream>>>(W1, W1t, 768, 3072);
    transpose_bf16<<<dim3(24, 96), tb, 0, stream>>>(W2, W2t, 3072, 768);

    // h = LN1(x)
    ln_kernel<<<8192, 256, 0, stream>>>(x, g1, be1, h_bf);
    // qkv = h @ [Wq|Wk|Wv]  (bf16 out)
    mfma_gemm<<<dim3(18, 64), 256, 0, stream>>>(h_bf, Wqkvt, nullptr, nullptr, nullptr, qkv_bf, 2304, 768, 0);
    // o = causal-softmax(q k^T * 768^-.5) v  (bf16 out)
    attn_mfma<<<dim3(16, 96), 256, 0, stream>>>(qkv_bf, o_bf);
    // x2 = x + o @ Wo + bo
    mfma_gemm<<<dim3(6, 64), 256, 0, stream>>>(o_bf, Wot, bo, x, x2, nullptr, 768, 768, 0);
    // h = LN2(x2)
    ln_kernel<<<8192, 256, 0, stream>>>(x2, g2, be2, h_bf);
    // ff1 = gelu(h @ W1 + b1)  (bf16 out)
    mfma_gemm<<<dim3(24, 64), 256, 0, stream>>>(h_bf, W1t, b1, nullptr, nullptr, ff1_bf, 3072, 768, 1);
    // out = x2 + ff1 @ W2 + b2
    mfma_gemm<<<dim3(6, 64), 256, 0, stream>>>(ff1_bf, W2t, b2, x2, out, nullptr, 768, 3072, 0);
}

// Round 5
// 397.948 us; speedup vs baseline: 12.5495x; 1.0868x over previous
//
#include <hip/hip_runtime.h>
#include <math.h>
#include <stdint.h>

typedef unsigned short u16;
typedef unsigned int u32;
typedef __attribute__((ext_vector_type(8))) __bf16 bf16x8;
typedef __attribute__((ext_vector_type(4))) float f32x4;

#define AS1 __attribute__((address_space(1)))
#define AS3 __attribute__((address_space(3)))

__device__ __forceinline__ void stage16(const void* g, void* l) {
    __builtin_amdgcn_global_load_lds((const AS1 void*)(uintptr_t)g,
                                     (AS3 void*)(uintptr_t)l, 16, 0, 0);
}

__device__ __forceinline__ u16 f2bf(float f) {
    u32 u = __float_as_uint(f);
    u += 0x7fffu + ((u >> 16) & 1u);
    return (u16)(u >> 16);
}

// ---------------- LayerNorm: 256 thr per row of 768, bf16 out ----------------
__global__ __launch_bounds__(256) void ln_kernel(const float* __restrict__ x,
                                                 const float* __restrict__ g,
                                                 const float* __restrict__ b,
                                                 u16* __restrict__ out) {
    int row = blockIdx.x;
    int tid = threadIdx.x;
    const float* xr = x + (size_t)row * 768;
    float x0 = xr[tid], x1 = xr[tid + 256], x2 = xr[tid + 512];

    __shared__ float red[256];
    red[tid] = x0 + x1 + x2;
    __syncthreads();
    for (int off = 128; off > 0; off >>= 1) {
        if (tid < off) red[tid] += red[tid + off];
        __syncthreads();
    }
    float mu = red[0] * (1.0f / 768.0f);
    __syncthreads();

    float d0 = x0 - mu, d1 = x1 - mu, d2 = x2 - mu;
    red[tid] = d0 * d0 + d1 * d1 + d2 * d2;
    __syncthreads();
    for (int off = 128; off > 0; off >>= 1) {
        if (tid < off) red[tid] += red[tid + off];
        __syncthreads();
    }
    float var = red[0] * (1.0f / 768.0f);
    float rs = rsqrtf(var + 1e-5f);

    u16* orow = out + (size_t)row * 768;
    orow[tid]       = f2bf(d0 * rs * g[tid]       + b[tid]);
    orow[tid + 256] = f2bf(d1 * rs * g[tid + 256] + b[tid + 256]);
    orow[tid + 512] = f2bf(d2 * rs * g[tid + 512] + b[tid + 512]);
}

// ---------------- transpose + fp32->bf16 convert: W[K][N] -> Wt[N][K] ----------------
__global__ __launch_bounds__(256) void transpose_bf16(const float* __restrict__ W,
                                                      u16* __restrict__ Wt,
                                                      int K, int N) {
    __shared__ float t[32][33];
    int tx = threadIdx.x, ty = threadIdx.y;
    int n0 = blockIdx.x * 32, k0 = blockIdx.y * 32;
#pragma unroll
    for (int j = 0; j < 32; j += 8)
        t[ty + j][tx] = W[(size_t)(k0 + ty + j) * N + n0 + tx];
    __syncthreads();
#pragma unroll
    for (int j = 0; j < 32; j += 8)
        Wt[(size_t)(n0 + ty + j) * K + k0 + tx] = f2bf(t[tx][ty + j]);
}

// ---------------- V transpose: qkv v-region [8192][2304] -> Vt[96][64][1024] ----------------
__global__ __launch_bounds__(256) void vt_kernel(const u16* __restrict__ qkv,
                                                 u16* __restrict__ Vt) {
    __shared__ u16 t[32][34];
    const int tx = threadIdx.x, ty = threadIdx.y;
    const int s0 = blockIdx.x * 32, d0 = blockIdx.y * 32, bh = blockIdx.z;
    const int b = bh / 12, h = bh % 12;
#pragma unroll
    for (int j = 0; j < 32; j += 8)
        t[ty + j][tx] = qkv[((size_t)(b * 1024) + s0 + ty + j) * 2304 + 1536 + h * 64 + d0 + tx];
    __syncthreads();
#pragma unroll
    for (int j = 0; j < 32; j += 8)
        Vt[((size_t)bh * 64 + d0 + ty + j) * 1024 + s0 + tx] = t[tx][ty + j];
}

// ---------------- bf16 MFMA GEMM, dbuf BK=64, swizzled LDS, counted vmcnt ----------------
// A: [M][K] bf16 row-major. Bt: [N][K] bf16 row-major.
// 128x128 tile, 4 waves (2x2). LDS: 2 x (A 16KB + B 16KB) = 64KB.
__global__ __launch_bounds__(256) void mfma_gemm(
    const u16* __restrict__ A, const u16* __restrict__ Bt,
    const float* __restrict__ bias, const float* __restrict__ res,
    float* __restrict__ outF, u16* __restrict__ outB,
    int N, int K, int act) {
    __shared__ char lds[65536];
    const int tid = threadIdx.x, lane = tid & 63, wid = tid >> 6;
    const int l15 = lane & 15, lk = lane >> 4;
    const int wrow = (wid >> 1) * 64, wcol = (wid & 1) * 64;

    // bijective XCD swizzle (all launch grids have nwg % 8 == 0)
    int wg = blockIdx.y * gridDim.x + blockIdx.x;
    const int nwg = gridDim.x * gridDim.y;
    wg = (wg & 7) * (nwg >> 3) + (wg >> 3);
    const int brow = (wg / gridDim.x) * 128;
    const int bcol = (wg % gridDim.x) * 128;

    const size_t K2 = (size_t)K * 2;
    const char* Abase = (const char*)A + (size_t)brow * K2;
    const char* Bbase = (const char*)Bt + (size_t)bcol * K2;

    // staging geometry: 4 rounds x 256 thr x 16B = 16KB per operand tile.
    int srow[4], scol[4];
#pragma unroll
    for (int j = 0; j < 4; ++j) {
        const int L = j * 4096 + tid * 16;
        srow[j] = L >> 7;
        scol[j] = (L & 127) ^ ((srow[j] & 7) << 4);
    }

    f32x4 acc[4][4] = {};
    const int nt = K >> 6;

    // prologue: stage tile 0 into buf 0, full drain
#pragma unroll
    for (int j = 0; j < 4; ++j) {
        const size_t off = (size_t)srow[j] * K2 + scol[j];
        stage16(Abase + off, lds + j * 4096 + tid * 16);
        stage16(Bbase + off, lds + 16384 + j * 4096 + tid * 16);
    }
    __syncthreads();

    for (int t = 0; t < nt; ++t) {
        if (t + 1 < nt) {
            const char* An = Abase + (size_t)(t + 1) * 128;
            const char* Bn = Bbase + (size_t)(t + 1) * 128;
            char* dst = lds + ((t + 1) & 1) * 32768;
#pragma unroll
            for (int j = 0; j < 4; ++j) {
                const size_t off = (size_t)srow[j] * K2 + scol[j];
                stage16(An + off, dst + j * 4096 + tid * 16);
                stage16(Bn + off, dst + 16384 + j * 4096 + tid * 16);
            }
            // wait only for tile t's 8 loads; tile t+1's stay in flight
            asm volatile("s_waitcnt vmcnt(8)\n\ts_barrier" ::: "memory");
        } else {
            asm volatile("s_waitcnt vmcnt(0)\n\ts_barrier" ::: "memory");
        }
        __builtin_amdgcn_sched_barrier(0);

        const char* As = lds + (t & 1) * 32768;
        const char* Bs = As + 16384;
#pragma unroll
        for (int kc = 0; kc < 2; ++kc) {
            bf16x8 af[4], bfv[4];
#pragma unroll
            for (int m = 0; m < 4; ++m) {
                const int row = wrow + m * 16 + l15;
                af[m] = *(const bf16x8*)(As + row * 128 +
                                         ((kc * 64 + lk * 16) ^ ((row & 7) << 4)));
            }
#pragma unroll
            for (int n = 0; n < 4; ++n) {
                const int row = wcol + n * 16 + l15;
                bfv[n] = *(const bf16x8*)(Bs + row * 128 +
                                          ((kc * 64 + lk * 16) ^ ((row & 7) << 4)));
            }
#pragma unroll
            for (int m = 0; m < 4; ++m)
#pragma unroll
                for (int n = 0; n < 4; ++n)
                    acc[m][n] = __builtin_amdgcn_mfma_f32_16x16x32_bf16(af[m], bfv[n], acc[m][n], 0, 0, 0);
        }
        // protect buf (t&1) before next iteration's prefetch overwrites buf (t+1)&1's partner
        asm volatile("s_barrier" ::: "memory");
    }

#pragma unroll
    for (int m = 0; m < 4; ++m)
#pragma unroll
        for (int n = 0; n < 4; ++n)
#pragma unroll
            for (int r = 0; r < 4; ++r) {
                int row = brow + wrow + m * 16 + lk * 4 + r;
                int col = bcol + wcol + n * 16 + l15;
                float v = acc[m][n][r];
                if (bias) v += bias[col];
                if (act) v = 0.5f * v * (1.0f + erff(v * 0.70710678118654752f));
                if (res) v += res[(size_t)row * N + col];
                if (outB) outB[(size_t)row * N + col] = f2bf(v);
                else outF[(size_t)row * N + col] = v;
            }
}

// ---------------- MFMA flash attention, pipelined gload_lds staging ----------------
// qkv bf16 [8192][2304]; Vt bf16 [96][64][1024].
// Block: 64 q-rows x one (b,h). 4 waves, wave w owns q-rows 16w..16w+15.
// LDS: dbuf { K [64s][64d] 8KB + Vt [64d][64s] 8KB } x2 = 32KB, P 4x2KB = 40KB.
__global__ __launch_bounds__(256) void attn_mfma(const u16* __restrict__ qkv,
                                                 const u16* __restrict__ Vt,
                                                 u16* __restrict__ obf) {
    __shared__ char lds[40960];
    const int tid = threadIdx.x, lane = tid & 63, w = tid >> 6;
    const int g = lane >> 4, l15 = lane & 15;

    int wg = blockIdx.y * gridDim.x + blockIdx.x;
    const int nwg = gridDim.x * gridDim.y;
    wg = (wg & 7) * (nwg >> 3) + (wg >> 3);
    const int qb = 15 - (wg & 15);          // heavy tiles first within each chunk
    const int bh = wg >> 4;
    const int h = bh % 12, b = bh / 12;
    const int t0 = qb * 64;
    const float scale = 0.03608439182435161f;  // 768^-0.5 (C, not hs, per reference)

    // Q fragments (A-operand) in registers
    const size_t qrow = ((size_t)b * 1024 + t0 + 16 * w + l15) * 2304 + h * 64;
    const bf16x8 qf0 = *(const bf16x8*)(qkv + qrow + 8 * g);
    const bf16x8 qf1 = *(const bf16x8*)(qkv + qrow + 8 * g + 32);

    // staging source pointers (pre-swizzled): this thread covers rows r0, r0+8
    const int sub = ((lane & 7) * 16) ^ ((lane >> 3) << 4);
    const int r0 = 16 * w + (lane >> 3);
    const char* kSrc = (const char*)qkv + ((size_t)(b * 1024 + r0) * 2304 + 768 + h * 64) * 2 + sub;
    const char* vSrc = (const char*)Vt + ((size_t)(bh * 64 + r0) * 1024) * 2 + sub;
    const int dstOff = 2 * w * 1024 + lane * 16;

    // prologue: stage tile 0 into buf 0, drain
    stage16(kSrc,            lds + dstOff);
    stage16(kSrc + 8 * 4608, lds + dstOff + 1024);
    stage16(vSrc,            lds + 8192 + dstOff);
    stage16(vSrc + 8 * 2048, lds + 8192 + dstOff + 1024);
    kSrc += 64 * 4608; vSrc += 128;
    __syncthreads();

    const int swzA = (l15 & 7) << 4;
    float m_r[4] = {-1e30f, -1e30f, -1e30f, -1e30f};
    float l_r[4] = {0.f, 0.f, 0.f, 0.f};
    f32x4 oacc[4] = {};
    char* Pw = lds + 32768 + w * 2048;

    for (int c = 0; c <= qb; ++c) {
        if (c < qb) {
            char* dst = lds + ((c + 1) & 1) * 16384;
            stage16(kSrc,            dst + dstOff);
            stage16(kSrc + 8 * 4608, dst + dstOff + 1024);
            stage16(vSrc,            dst + 8192 + dstOff);
            stage16(vSrc + 8 * 2048, dst + 8192 + dstOff + 1024);
            kSrc += 64 * 4608; vSrc += 128;
            asm volatile("s_waitcnt vmcnt(4)\n\ts_barrier" ::: "memory");
        } else {
            asm volatile("s_waitcnt vmcnt(0)\n\ts_barrier" ::: "memory");
        }
        __builtin_amdgcn_sched_barrier(0);

        const char* bufK = lds + (c & 1) * 16384;
        const char* bufV = bufK + 8192;

        // S = Q K^T : D[q=4g+r][s=l15+16st]
        f32x4 sacc[4] = {};
#pragma unroll
        for (int st = 0; st < 4; ++st) {
            const char* krow = bufK + (l15 + 16 * st) * 128;
            const bf16x8 kf0 = *(const bf16x8*)(krow + ((16 * g) ^ swzA));
            const bf16x8 kf1 = *(const bf16x8*)(krow + ((16 * g + 64) ^ swzA));
            sacc[st] = __builtin_amdgcn_mfma_f32_16x16x32_bf16(qf0, kf0, sacc[st], 0, 0, 0);
            sacc[st] = __builtin_amdgcn_mfma_f32_16x16x32_bf16(qf1, kf1, sacc[st], 0, 0, 0);
        }

        const bool diag = (c == qb);
#pragma unroll
        for (int r = 0; r < 4; ++r) {
            float sv0 = sacc[0][r] * scale, sv1 = sacc[1][r] * scale;
            float sv2 = sacc[2][r] * scale, sv3 = sacc[3][r] * scale;
            if (diag) {
                const int trel = 16 * w + 4 * g + r;
                if (l15 +  0 > trel) sv0 = -1e30f;
                if (l15 + 16 > trel) sv1 = -1e30f;
                if (l15 + 32 > trel) sv2 = -1e30f;
                if (l15 + 48 > trel) sv3 = -1e30f;
            }
            float mx = fmaxf(fmaxf(sv0, sv1), fmaxf(sv2, sv3));
#pragma unroll
            for (int off = 1; off < 16; off <<= 1) mx = fmaxf(mx, __shfl_xor(mx, off));
            const float mnew = fmaxf(m_r[r], mx);
            const float corr = __expf(m_r[r] - mnew);
            const float p0 = __expf(sv0 - mnew), p1 = __expf(sv1 - mnew);
            const float p2 = __expf(sv2 - mnew), p3 = __expf(sv3 - mnew);
            float ps = p0 + p1 + p2 + p3;
#pragma unroll
            for (int off = 1; off < 16; off <<= 1) ps += __shfl_xor(ps, off);
            l_r[r] = l_r[r] * corr + ps;
            m_r[r] = mnew;
            oacc[0][r] *= corr; oacc[1][r] *= corr;
            oacc[2][r] *= corr; oacc[3][r] *= corr;
            const int q = 4 * g + r;
            char* pr = Pw + q * 128;
            const int sw = (q & 7) << 4;
            *(u16*)(pr + ((l15 * 2 +  0) ^ sw)) = f2bf(p0);
            *(u16*)(pr + ((l15 * 2 + 32) ^ sw)) = f2bf(p1);
            *(u16*)(pr + ((l15 * 2 + 64) ^ sw)) = f2bf(p2);
            *(u16*)(pr + ((l15 * 2 + 96) ^ sw)) = f2bf(p3);
        }

        // O += P V : A = P[16q][32s-chunk], B = Vt rows (d-major)
#pragma unroll
        for (int kc = 0; kc < 2; ++kc) {
            const bf16x8 pa = *(const bf16x8*)(Pw + l15 * 128 + ((16 * g + 64 * kc) ^ swzA));
#pragma unroll
            for (int dt = 0; dt < 4; ++dt) {
                const int d = l15 + 16 * dt;
                const bf16x8 vf = *(const bf16x8*)(bufV + d * 128 +
                                   ((16 * g + 64 * kc) ^ ((d & 7) << 4)));
                oacc[dt] = __builtin_amdgcn_mfma_f32_16x16x32_bf16(pa, vf, oacc[dt], 0, 0, 0);
            }
        }
        asm volatile("s_barrier" ::: "memory");  // buffers safe to overwrite
    }

    const size_t orow0 = ((size_t)b * 1024 + t0 + 16 * w) * 768 + h * 64;
#pragma unroll
    for (int r = 0; r < 4; ++r) {
        const float inv = 1.0f / l_r[r];
        const size_t orow = orow0 + (size_t)(4 * g + r) * 768;
#pragma unroll
        for (int dt = 0; dt < 4; ++dt)
            obf[orow + 16 * dt + l15] = f2bf(oacc[dt][r] * inv);
    }
}

extern "C" void kernel_launch(void* const* d_in, const int* in_sizes, int n_in,
                              void* d_out, int out_size, void* d_ws, size_t ws_size,
                              hipStream_t stream) {
    const float* x   = (const float*)d_in[0];
    const float* Wq  = (const float*)d_in[1];
    const float* Wk  = (const float*)d_in[2];
    const float* Wv  = (const float*)d_in[3];
    const float* Wo  = (const float*)d_in[4];
    const float* bo  = (const float*)d_in[5];
    const float* W1  = (const float*)d_in[6];
    const float* b1  = (const float*)d_in[7];
    const float* W2  = (const float*)d_in[8];
    const float* b2  = (const float*)d_in[9];
    const float* g1  = (const float*)d_in[10];
    const float* be1 = (const float*)d_in[11];
    const float* g2  = (const float*)d_in[12];
    const float* be2 = (const float*)d_in[13];
    float* out = (float*)d_out;

    char* ws = (char*)d_ws;
    u16* qkv_bf = (u16*)(ws);              // [8192][2304] bf16  37.7MB (dead after attn)
    u16* ff1_bf = (u16*)(ws);              // [8192][3072] bf16  50.3MB (reuses qkv region)
    float* x2   = (float*)(ws + 50331648); // [8192][768]  f32   25.2MB
    u16* h_bf   = (u16*)(ws + 75497472);   // [8192][768]  bf16  12.6MB
    u16* o_bf   = (u16*)(ws + 88080384);   // [8192][768]  bf16  12.6MB
    u16* Wqkvt  = (u16*)(ws + 100663296);  // [2304][768]  bf16   3.5MB
    u16* W1t    = (u16*)(ws + 104202240);  // [3072][768]  bf16   4.7MB
    u16* W2t    = (u16*)(ws + 108920832);  // [768][3072]  bf16   4.7MB
    u16* Wot    = (u16*)(ws + 113639424);  // [768][768]   bf16   1.2MB
    u16* Vt     = (u16*)(ws + 114819072);  // [96][64][1024] bf16 12.6MB (dead after attn)

    dim3 tb(32, 8);
    transpose_bf16<<<dim3(24, 24), tb, 0, stream>>>(Wq, Wqkvt, 768, 768);
    transpose_bf16<<<dim3(24, 24), tb, 0, stream>>>(Wk, Wqkvt + 768 * 768, 768, 768);
    transpose_bf16<<<dim3(24, 24), tb, 0, stream>>>(Wv, Wqkvt + 2 * 768 * 768, 768, 768);
    transpose_bf16<<<dim3(24, 24), tb, 0, stream>>>(Wo, Wot, 768, 768);
    transpose_bf16<<<dim3(96, 24), tb, 0, stream>>>(W1, W1t, 768, 3072);
    transpose_bf16<<<dim3(24, 96), tb, 0, stream>>>(W2, W2t, 3072, 768);

    // h = LN1(x)
    ln_kernel<<<8192, 256, 0, stream>>>(x, g1, be1, h_bf);
    // qkv = h @ [Wq|Wk|Wv]  (bf16 out)
    mfma_gemm<<<dim3(18, 64), 256, 0, stream>>>(h_bf, Wqkvt, nullptr, nullptr, nullptr, qkv_bf, 2304, 768, 0);
    // Vt = per-head transpose of V
    vt_kernel<<<dim3(32, 2, 96), tb, 0, stream>>>(qkv_bf, Vt);
    // o = causal-softmax(q k^T * 768^-.5) v  (bf16 out)
    attn_mfma<<<dim3(16, 96), 256, 0, stream>>>(qkv_bf, Vt, o_bf);
    // x2 = x + o @ Wo + bo
    mfma_gemm<<<dim3(6, 64), 256, 0, stream>>>(o_bf, Wot, bo, x, x2, nullptr, 768, 768, 0);
    // h = LN2(x2)
    ln_kernel<<<8192, 256, 0, stream>>>(x2, g2, be2, h_bf);
    // ff1 = gelu(h @ W1 + b1)  (bf16 out)
    mfma_gemm<<<dim3(24, 64), 256, 0, stream>>>(h_bf, W1t, b1, nullptr, nullptr, ff1_bf, 3072, 768, 1);
    // out = x2 + ff1 @ W2 + b2
    mfma_gemm<<<dim3(6, 64), 256, 0, stream>>>(ff1_bf, W2t, b2, x2, out, nullptr, 768, 3072, 0);
}

// Round 6
// 375.271 us; speedup vs baseline: 13.3078x; 1.0604x over previous
//
#include <hip/hip_runtime.h>
#include <math.h>
#include <stdint.h>

typedef unsigned short u16;
typedef unsigned int u32;
typedef __attribute__((ext_vector_type(8))) __bf16 bf16x8;
typedef __attribute__((ext_vector_type(4))) float f32x4;

#define AS1 __attribute__((address_space(1)))
#define AS3 __attribute__((address_space(3)))

__device__ __forceinline__ void stage16(const void* g, void* l) {
    __builtin_amdgcn_global_load_lds((const AS1 void*)(uintptr_t)g,
                                     (AS3 void*)(uintptr_t)l, 16, 0, 0);
}

__device__ __forceinline__ u16 f2bf(float f) {
    u32 u = __float_as_uint(f);
    u += 0x7fffu + ((u >> 16) & 1u);
    return (u16)(u >> 16);
}

// ---------------- LayerNorm: 256 thr per row of 768, bf16 out ----------------
__global__ __launch_bounds__(256) void ln_kernel(const float* __restrict__ x,
                                                 const float* __restrict__ g,
                                                 const float* __restrict__ b,
                                                 u16* __restrict__ out) {
    int row = blockIdx.x;
    int tid = threadIdx.x;
    const float* xr = x + (size_t)row * 768;
    float x0 = xr[tid], x1 = xr[tid + 256], x2 = xr[tid + 512];

    __shared__ float red[256];
    red[tid] = x0 + x1 + x2;
    __syncthreads();
    for (int off = 128; off > 0; off >>= 1) {
        if (tid < off) red[tid] += red[tid + off];
        __syncthreads();
    }
    float mu = red[0] * (1.0f / 768.0f);
    __syncthreads();

    float d0 = x0 - mu, d1 = x1 - mu, d2 = x2 - mu;
    red[tid] = d0 * d0 + d1 * d1 + d2 * d2;
    __syncthreads();
    for (int off = 128; off > 0; off >>= 1) {
        if (tid < off) red[tid] += red[tid + off];
        __syncthreads();
    }
    float var = red[0] * (1.0f / 768.0f);
    float rs = rsqrtf(var + 1e-5f);

    u16* orow = out + (size_t)row * 768;
    orow[tid]       = f2bf(d0 * rs * g[tid]       + b[tid]);
    orow[tid + 256] = f2bf(d1 * rs * g[tid + 256] + b[tid + 256]);
    orow[tid + 512] = f2bf(d2 * rs * g[tid + 512] + b[tid + 512]);
}

// ---------------- transpose + fp32->bf16 convert: W[K][N] -> Wt[N][K] ----------------
__global__ __launch_bounds__(256) void transpose_bf16(const float* __restrict__ W,
                                                      u16* __restrict__ Wt,
                                                      int K, int N) {
    __shared__ float t[32][33];
    int tx = threadIdx.x, ty = threadIdx.y;
    int n0 = blockIdx.x * 32, k0 = blockIdx.y * 32;
#pragma unroll
    for (int j = 0; j < 32; j += 8)
        t[ty + j][tx] = W[(size_t)(k0 + ty + j) * N + n0 + tx];
    __syncthreads();
#pragma unroll
    for (int j = 0; j < 32; j += 8)
        Wt[(size_t)(n0 + ty + j) * K + k0 + tx] = f2bf(t[tx][ty + j]);
}

// ---------------- V transpose: qkv v-region [8192][2304] -> Vt[96][64][1024] ----------------
__global__ __launch_bounds__(256) void vt_kernel(const u16* __restrict__ qkv,
                                                 u16* __restrict__ Vt) {
    __shared__ u16 t[32][34];
    const int tx = threadIdx.x, ty = threadIdx.y;
    const int s0 = blockIdx.x * 32, d0 = blockIdx.y * 32, bh = blockIdx.z;
    const int b = bh / 12, h = bh % 12;
#pragma unroll
    for (int j = 0; j < 32; j += 8)
        t[ty + j][tx] = qkv[((size_t)(b * 1024) + s0 + ty + j) * 2304 + 1536 + h * 64 + d0 + tx];
    __syncthreads();
#pragma unroll
    for (int j = 0; j < 32; j += 8)
        Vt[((size_t)bh * 64 + d0 + ty + j) * 1024 + s0 + tx] = t[tx][ty + j];
}

// ---------------- bf16 MFMA GEMM, dbuf BK=32 (32KB LDS), counted vmcnt ----------------
// A: [M][K] bf16 row-major. Bt: [N][K] bf16 row-major.
// 128x128 tile, 4 waves (2x2). LDS: 2 x (A 8KB + B 8KB) = 32KB -> ~4 blocks/CU.
// Rows are 64B; byte-in-row XOR-swizzled by ((row&3)<<4) (4-way residual conflict).
__global__ __launch_bounds__(256) void mfma_gemm(
    const u16* __restrict__ A, const u16* __restrict__ Bt,
    const float* __restrict__ bias, const float* __restrict__ res,
    float* __restrict__ outF, u16* __restrict__ outB,
    int N, int K, int act) {
    __shared__ char lds[32768];
    const int tid = threadIdx.x, lane = tid & 63, wid = tid >> 6;
    const int l15 = lane & 15, lk = lane >> 4;
    const int wrow = (wid >> 1) * 64, wcol = (wid & 1) * 64;

    // bijective XCD swizzle (all launch grids have nwg % 8 == 0)
    int wg = blockIdx.y * gridDim.x + blockIdx.x;
    const int nwg = gridDim.x * gridDim.y;
    wg = (wg & 7) * (nwg >> 3) + (wg >> 3);
    const int brow = (wg / gridDim.x) * 128;
    const int bcol = (wg % gridDim.x) * 128;

    const size_t K2 = (size_t)K * 2;
    const char* Abase = (const char*)A + (size_t)brow * K2;
    const char* Bbase = (const char*)Bt + (size_t)bcol * K2;

    // staging geometry: 2 rounds x 256 thr x 16B = 8KB per operand tile.
    // LDS linear L = j*4096 + tid*16; logical row = L>>6, col = (L&63)^((row&3)<<4)
    int srow[2], scol[2];
#pragma unroll
    for (int j = 0; j < 2; ++j) {
        const int L = j * 4096 + tid * 16;
        srow[j] = L >> 6;
        scol[j] = (L & 63) ^ ((srow[j] & 3) << 4);
    }

    f32x4 acc[4][4] = {};
    const int nt = K >> 5;

    // prologue: stage tile 0 into buf 0, full drain
#pragma unroll
    for (int j = 0; j < 2; ++j) {
        const size_t off = (size_t)srow[j] * K2 + scol[j];
        stage16(Abase + off, lds + j * 4096 + tid * 16);
        stage16(Bbase + off, lds + 8192 + j * 4096 + tid * 16);
    }
    __syncthreads();

    for (int t = 0; t < nt; ++t) {
        if (t + 1 < nt) {
            const char* An = Abase + (size_t)(t + 1) * 64;
            const char* Bn = Bbase + (size_t)(t + 1) * 64;
            char* dst = lds + ((t + 1) & 1) * 16384;
#pragma unroll
            for (int j = 0; j < 2; ++j) {
                const size_t off = (size_t)srow[j] * K2 + scol[j];
                stage16(An + off, dst + j * 4096 + tid * 16);
                stage16(Bn + off, dst + 8192 + j * 4096 + tid * 16);
            }
            // wait only for tile t's 4 loads; tile t+1's stay in flight
            asm volatile("s_waitcnt vmcnt(4)\n\ts_barrier" ::: "memory");
        } else {
            asm volatile("s_waitcnt vmcnt(0)\n\ts_barrier" ::: "memory");
        }
        __builtin_amdgcn_sched_barrier(0);

        const char* As = lds + (t & 1) * 16384;
        const char* Bs = As + 8192;
        bf16x8 af[4], bfv[4];
#pragma unroll
        for (int m = 0; m < 4; ++m) {
            const int row = wrow + m * 16 + l15;
            af[m] = *(const bf16x8*)(As + row * 64 + ((lk * 16) ^ ((row & 3) << 4)));
        }
#pragma unroll
        for (int n = 0; n < 4; ++n) {
            const int row = wcol + n * 16 + l15;
            bfv[n] = *(const bf16x8*)(Bs + row * 64 + ((lk * 16) ^ ((row & 3) << 4)));
        }
#pragma unroll
        for (int m = 0; m < 4; ++m)
#pragma unroll
            for (int n = 0; n < 4; ++n)
                acc[m][n] = __builtin_amdgcn_mfma_f32_16x16x32_bf16(af[m], bfv[n], acc[m][n], 0, 0, 0);

        // protect buf (t&1) before next iteration's prefetch overwrites it
        asm volatile("s_barrier" ::: "memory");
    }

#pragma unroll
    for (int m = 0; m < 4; ++m)
#pragma unroll
        for (int n = 0; n < 4; ++n)
#pragma unroll
            for (int r = 0; r < 4; ++r) {
                int row = brow + wrow + m * 16 + lk * 4 + r;
                int col = bcol + wcol + n * 16 + l15;
                float v = acc[m][n][r];
                if (bias) v += bias[col];
                if (act) v = 0.5f * v * (1.0f + erff(v * 0.70710678118654752f));
                if (res) v += res[(size_t)row * N + col];
                if (outB) outB[(size_t)row * N + col] = f2bf(v);
                else outF[(size_t)row * N + col] = v;
            }
}

// ---------------- MFMA flash attention, pipelined gload_lds staging ----------------
// qkv bf16 [8192][2304]; Vt bf16 [96][64][1024].
// Block: 64 q-rows x one (b,h). 4 waves, wave w owns q-rows 16w..16w+15.
// LDS: dbuf { K [64s][64d] 8KB + Vt [64d][64s] 8KB } x2 = 32KB, P 4x2KB = 40KB.
__global__ __launch_bounds__(256) void attn_mfma(const u16* __restrict__ qkv,
                                                 const u16* __restrict__ Vt,
                                                 u16* __restrict__ obf) {
    __shared__ char lds[40960];
    const int tid = threadIdx.x, lane = tid & 63, w = tid >> 6;
    const int g = lane >> 4, l15 = lane & 15;

    int wg = blockIdx.y * gridDim.x + blockIdx.x;
    const int nwg = gridDim.x * gridDim.y;
    wg = (wg & 7) * (nwg >> 3) + (wg >> 3);
    const int qb = 15 - (wg & 15);          // heavy tiles first within each chunk
    const int bh = wg >> 4;
    const int h = bh % 12, b = bh / 12;
    const int t0 = qb * 64;
    const float scale = 0.03608439182435161f;  // 768^-0.5 (C, not hs, per reference)

    // Q fragments (A-operand) in registers
    const size_t qrow = ((size_t)b * 1024 + t0 + 16 * w + l15) * 2304 + h * 64;
    const bf16x8 qf0 = *(const bf16x8*)(qkv + qrow + 8 * g);
    const bf16x8 qf1 = *(const bf16x8*)(qkv + qrow + 8 * g + 32);

    // staging source pointers (pre-swizzled): this thread covers rows r0, r0+8
    const int sub = ((lane & 7) * 16) ^ ((lane >> 3) << 4);
    const int r0 = 16 * w + (lane >> 3);
    const char* kSrc = (const char*)qkv + ((size_t)(b * 1024 + r0) * 2304 + 768 + h * 64) * 2 + sub;
    const char* vSrc = (const char*)Vt + ((size_t)(bh * 64 + r0) * 1024) * 2 + sub;
    const int dstOff = 2 * w * 1024 + lane * 16;

    // prologue: stage tile 0 into buf 0, drain
    stage16(kSrc,            lds + dstOff);
    stage16(kSrc + 8 * 4608, lds + dstOff + 1024);
    stage16(vSrc,            lds + 8192 + dstOff);
    stage16(vSrc + 8 * 2048, lds + 8192 + dstOff + 1024);
    kSrc += 64 * 4608; vSrc += 128;
    __syncthreads();

    const int swzA = (l15 & 7) << 4;
    float m_r[4] = {-1e30f, -1e30f, -1e30f, -1e30f};
    float l_r[4] = {0.f, 0.f, 0.f, 0.f};
    f32x4 oacc[4] = {};
    char* Pw = lds + 32768 + w * 2048;

    for (int c = 0; c <= qb; ++c) {
        if (c < qb) {
            char* dst = lds + ((c + 1) & 1) * 16384;
            stage16(kSrc,            dst + dstOff);
            stage16(kSrc + 8 * 4608, dst + dstOff + 1024);
            stage16(vSrc,            dst + 8192 + dstOff);
            stage16(vSrc + 8 * 2048, dst + 8192 + dstOff + 1024);
            kSrc += 64 * 4608; vSrc += 128;
            asm volatile("s_waitcnt vmcnt(4)\n\ts_barrier" ::: "memory");
        } else {
            asm volatile("s_waitcnt vmcnt(0)\n\ts_barrier" ::: "memory");
        }
        __builtin_amdgcn_sched_barrier(0);

        const char* bufK = lds + (c & 1) * 16384;
        const char* bufV = bufK + 8192;

        // S = Q K^T : D[q=4g+r][s=l15+16st]
        f32x4 sacc[4] = {};
#pragma unroll
        for (int st = 0; st < 4; ++st) {
            const char* krow = bufK + (l15 + 16 * st) * 128;
            const bf16x8 kf0 = *(const bf16x8*)(krow + ((16 * g) ^ swzA));
            const bf16x8 kf1 = *(const bf16x8*)(krow + ((16 * g + 64) ^ swzA));
            sacc[st] = __builtin_amdgcn_mfma_f32_16x16x32_bf16(qf0, kf0, sacc[st], 0, 0, 0);
            sacc[st] = __builtin_amdgcn_mfma_f32_16x16x32_bf16(qf1, kf1, sacc[st], 0, 0, 0);
        }

        const bool diag = (c == qb);
#pragma unroll
        for (int r = 0; r < 4; ++r) {
            float sv0 = sacc[0][r] * scale, sv1 = sacc[1][r] * scale;
            float sv2 = sacc[2][r] * scale, sv3 = sacc[3][r] * scale;
            if (diag) {
                const int trel = 16 * w + 4 * g + r;
                if (l15 +  0 > trel) sv0 = -1e30f;
                if (l15 + 16 > trel) sv1 = -1e30f;
                if (l15 + 32 > trel) sv2 = -1e30f;
                if (l15 + 48 > trel) sv3 = -1e30f;
            }
            float mx = fmaxf(fmaxf(sv0, sv1), fmaxf(sv2, sv3));
#pragma unroll
            for (int off = 1; off < 16; off <<= 1) mx = fmaxf(mx, __shfl_xor(mx, off));
            const float mnew = fmaxf(m_r[r], mx);
            const float corr = __expf(m_r[r] - mnew);
            const float p0 = __expf(sv0 - mnew), p1 = __expf(sv1 - mnew);
            const float p2 = __expf(sv2 - mnew), p3 = __expf(sv3 - mnew);
            float ps = p0 + p1 + p2 + p3;
#pragma unroll
            for (int off = 1; off < 16; off <<= 1) ps += __shfl_xor(ps, off);
            l_r[r] = l_r[r] * corr + ps;
            m_r[r] = mnew;
            oacc[0][r] *= corr; oacc[1][r] *= corr;
            oacc[2][r] *= corr; oacc[3][r] *= corr;
            const int q = 4 * g + r;
            char* pr = Pw + q * 128;
            const int sw = (q & 7) << 4;
            *(u16*)(pr + ((l15 * 2 +  0) ^ sw)) = f2bf(p0);
            *(u16*)(pr + ((l15 * 2 + 32) ^ sw)) = f2bf(p1);
            *(u16*)(pr + ((l15 * 2 + 64) ^ sw)) = f2bf(p2);
            *(u16*)(pr + ((l15 * 2 + 96) ^ sw)) = f2bf(p3);
        }

        // O += P V : A = P[16q][32s-chunk], B = Vt rows (d-major)
#pragma unroll
        for (int kc = 0; kc < 2; ++kc) {
            const bf16x8 pa = *(const bf16x8*)(Pw + l15 * 128 + ((16 * g + 64 * kc) ^ swzA));
#pragma unroll
            for (int dt = 0; dt < 4; ++dt) {
                const int d = l15 + 16 * dt;
                const bf16x8 vf = *(const bf16x8*)(bufV + d * 128 +
                                   ((16 * g + 64 * kc) ^ ((d & 7) << 4)));
                oacc[dt] = __builtin_amdgcn_mfma_f32_16x16x32_bf16(pa, vf, oacc[dt], 0, 0, 0);
            }
        }
        asm volatile("s_barrier" ::: "memory");  // buffers safe to overwrite
    }

    const size_t orow0 = ((size_t)b * 1024 + t0 + 16 * w) * 768 + h * 64;
#pragma unroll
    for (int r = 0; r < 4; ++r) {
        const float inv = 1.0f / l_r[r];
        const size_t orow = orow0 + (size_t)(4 * g + r) * 768;
#pragma unroll
        for (int dt = 0; dt < 4; ++dt)
            obf[orow + 16 * dt + l15] = f2bf(oacc[dt][r] * inv);
    }
}

extern "C" void kernel_launch(void* const* d_in, const int* in_sizes, int n_in,
                              void* d_out, int out_size, void* d_ws, size_t ws_size,
                              hipStream_t stream) {
    const float* x   = (const float*)d_in[0];
    const float* Wq  = (const float*)d_in[1];
    const float* Wk  = (const float*)d_in[2];
    const float* Wv  = (const float*)d_in[3];
    const float* Wo  = (const float*)d_in[4];
    const float* bo  = (const float*)d_in[5];
    const float* W1  = (const float*)d_in[6];
    const float* b1  = (const float*)d_in[7];
    const float* W2  = (const float*)d_in[8];
    const float* b2  = (const float*)d_in[9];
    const float* g1  = (const float*)d_in[10];
    const float* be1 = (const float*)d_in[11];
    const float* g2  = (const float*)d_in[12];
    const float* be2 = (const float*)d_in[13];
    float* out = (float*)d_out;

    char* ws = (char*)d_ws;
    u16* qkv_bf = (u16*)(ws);              // [8192][2304] bf16  37.7MB (dead after attn)
    u16* ff1_bf = (u16*)(ws);              // [8192][3072] bf16  50.3MB (reuses qkv region)
    float* x2   = (float*)(ws + 50331648); // [8192][768]  f32   25.2MB
    u16* h_bf   = (u16*)(ws + 75497472);   // [8192][768]  bf16  12.6MB
    u16* o_bf   = (u16*)(ws + 88080384);   // [8192][768]  bf16  12.6MB
    u16* Wqkvt  = (u16*)(ws + 100663296);  // [2304][768]  bf16   3.5MB
    u16* W1t    = (u16*)(ws + 104202240);  // [3072][768]  bf16   4.7MB
    u16* W2t    = (u16*)(ws + 108920832);  // [768][3072]  bf16   4.7MB
    u16* Wot    = (u16*)(ws + 113639424);  // [768][768]   bf16   1.2MB
    u16* Vt     = (u16*)(ws + 114819072);  // [96][64][1024] bf16 12.6MB (dead after attn)

    dim3 tb(32, 8);
    transpose_bf16<<<dim3(24, 24), tb, 0, stream>>>(Wq, Wqkvt, 768, 768);
    transpose_bf16<<<dim3(24, 24), tb, 0, stream>>>(Wk, Wqkvt + 768 * 768, 768, 768);
    transpose_bf16<<<dim3(24, 24), tb, 0, stream>>>(Wv, Wqkvt + 2 * 768 * 768, 768, 768);
    transpose_bf16<<<dim3(24, 24), tb, 0, stream>>>(Wo, Wot, 768, 768);
    transpose_bf16<<<dim3(96, 24), tb, 0, stream>>>(W1, W1t, 768, 3072);
    transpose_bf16<<<dim3(24, 96), tb, 0, stream>>>(W2, W2t, 3072, 768);

    // h = LN1(x)
    ln_kernel<<<8192, 256, 0, stream>>>(x, g1, be1, h_bf);
    // qkv = h @ [Wq|Wk|Wv]  (bf16 out)
    mfma_gemm<<<dim3(18, 64), 256, 0, stream>>>(h_bf, Wqkvt, nullptr, nullptr, nullptr, qkv_bf, 2304, 768, 0);
    // Vt = per-head transpose of V
    vt_kernel<<<dim3(32, 2, 96), tb, 0, stream>>>(qkv_bf, Vt);
    // o = causal-softmax(q k^T * 768^-.5) v  (bf16 out)
    attn_mfma<<<dim3(16, 96), 256, 0, stream>>>(qkv_bf, Vt, o_bf);
    // x2 = x + o @ Wo + bo
    mfma_gemm<<<dim3(6, 64), 256, 0, stream>>>(o_bf, Wot, bo, x, x2, nullptr, 768, 768, 0);
    // h = LN2(x2)
    ln_kernel<<<8192, 256, 0, stream>>>(x2, g2, be2, h_bf);
    // ff1 = gelu(h @ W1 + b1)  (bf16 out)
    mfma_gemm<<<dim3(24, 64), 256, 0, stream>>>(h_bf, W1t, b1, nullptr, nullptr, ff1_bf, 3072, 768, 1);
    // out = x2 + ff1 @ W2 + b2
    mfma_gemm<<<dim3(6, 64), 256, 0, stream>>>(ff1_bf, W2t, b2, x2, out, nullptr, 768, 3072, 0);
}